// Round 5
// baseline (551.226 us; speedup 1.0000x reference)
//
#include <hip/hip_runtime.h>

#define NNODES 50000
#define NEDGES 500000
#define DIM    384
#define NB     64
#define SLOPE  0.2f
#define LN_EPS 1e-5f
#define EPRIME (NEDGES + NNODES)
#define POOLS  16
#define SCANB  256
#define NSCB   ((NNODES + SCANB - 1) / SCANB)   // 196

typedef __attribute__((ext_vector_type(8))) short short8;
typedef __attribute__((ext_vector_type(4))) float floatx4;
typedef __attribute__((ext_vector_type(2))) float floatx2;

// ---------- helpers ----------
__device__ __forceinline__ int load_i(const void* p, long long i, int is64) {
  return is64 ? (int)((const long long*)p)[i] : ((const int*)p)[i];
}
__device__ __forceinline__ unsigned short f2bf(float f) {
  unsigned u = __float_as_uint(f);
  u += 0x7fffu + ((u >> 16) & 1u);
  return (unsigned short)(u >> 16);
}
__device__ __forceinline__ float bf2f(unsigned short u) {
  return __uint_as_float(((unsigned)u) << 16);
}

// ---------- dtype detect (int64 vs int32) ----------
__global__ void detect_kernel(const int* __restrict__ ei32, int* __restrict__ flag) {
  __shared__ int nz;
  if (threadIdx.x == 0) nz = 0;
  __syncthreads();
  if (ei32[2 * threadIdx.x + 1] != 0) atomicAdd(&nz, 1);
  __syncthreads();
  if (threadIdx.x == 0) *flag = (nz == 0) ? 1 : 0;
}

// ---------- CSR build ----------
__global__ void count_kernel(const void* __restrict__ ei, const int* __restrict__ flag,
                             int* __restrict__ deg) {
  int is64 = *flag;
  for (int i = blockIdx.x * blockDim.x + threadIdx.x; i < EPRIME; i += gridDim.x * blockDim.x) {
    int d = (i < NEDGES) ? load_i(ei, (long long)NEDGES + i, is64) : (i - NEDGES);
    atomicAdd(&deg[d], 1);
  }
}

__global__ void scan1_kernel(const int* __restrict__ deg, int* __restrict__ row_ptr,
                             int* __restrict__ btot) {
  __shared__ int buf[SCANB];
  int t = threadIdx.x, idx = blockIdx.x * SCANB + t;
  int v = (idx < NNODES) ? deg[idx] : 0;
  buf[t] = v;
  __syncthreads();
  for (int off = 1; off < SCANB; off <<= 1) {
    int x = (t >= off) ? buf[t - off] : 0;
    __syncthreads();
    buf[t] += x;
    __syncthreads();
  }
  if (idx < NNODES) row_ptr[idx] = buf[t] - v;
  if (t == SCANB - 1) btot[blockIdx.x] = buf[t];
}
__global__ void scan2_kernel(int* __restrict__ btot) {
  __shared__ int buf[256];
  int t = threadIdx.x;
  int v = (t < NSCB) ? btot[t] : 0;
  buf[t] = v;
  __syncthreads();
  for (int off = 1; off < 256; off <<= 1) {
    int x = (t >= off) ? buf[t - off] : 0;
    __syncthreads();
    buf[t] += x;
    __syncthreads();
  }
  if (t < NSCB) btot[t] = buf[t] - v;
}
__global__ void scan3_kernel(int* __restrict__ row_ptr, int* __restrict__ cursor,
                             const int* __restrict__ btot) {
  int idx = blockIdx.x * SCANB + threadIdx.x;
  if (idx < NNODES) {
    int v = row_ptr[idx] + btot[blockIdx.x];
    row_ptr[idx] = v;
    cursor[idx] = v;
  }
  if (idx == 0) row_ptr[NNODES] = EPRIME;
}

__global__ void scatter_kernel(const void* __restrict__ ei, const int* __restrict__ flag,
                               int* __restrict__ cursor, int* __restrict__ srt) {
  int is64 = *flag;
  for (int i = blockIdx.x * blockDim.x + threadIdx.x; i < EPRIME; i += gridDim.x * blockDim.x) {
    int s, d;
    if (i < NEDGES) { s = load_i(ei, i, is64); d = load_i(ei, (long long)NEDGES + i, is64); }
    else            { s = d = i - NEDGES; }
    int pos = atomicAdd(&cursor[d], 1);
    srt[pos] = s;
  }
}

// ---------- conversions ----------
__global__ void convert_x_kernel(const float* __restrict__ x, unsigned short* __restrict__ xb) {
  int i = blockIdx.x * blockDim.x + threadIdx.x;
  float4 v = ((const float4*)x)[i];
  ushort4 o;
  o.x = f2bf(v.x); o.y = f2bf(v.y); o.z = f2bf(v.z); o.w = f2bf(v.w);
  ((ushort4*)xb)[i] = o;
}

__global__ void convert_w_kernel(const float* __restrict__ W1, const float* __restrict__ W2,
                                 const float* __restrict__ W3, unsigned short* __restrict__ Wt) {
  const float* W = (blockIdx.y == 0) ? W1 : (blockIdx.y == 1) ? W2 : W3;
  unsigned short* o = Wt + (size_t)blockIdx.y * DIM * DIM;
  int n = blockIdx.x;
  int k = threadIdx.x;
  o[n * DIM + k] = f2bf(W[k * DIM + n]);
}

// ---------- bf16 MFMA GEMM -> fp8 e4m3 output (h only ever consumed as fp8) ----------
__global__ __launch_bounds__(256)
void gemm_bf16_kernel(const unsigned short* __restrict__ A,
                      const unsigned short* __restrict__ Bt,
                      unsigned char* __restrict__ C8, int M) {
  __shared__ unsigned short As[128 * 32];
  __shared__ unsigned short Bs[128 * 32];
  int tid = threadIdx.x;
  int lane = tid & 63;
  int wave = tid >> 6;
  int bm = blockIdx.x * 128;
  int bn = blockIdx.y * 128;
  int wm = (wave & 1) * 64;
  int wn = (wave >> 1) * 64;
  int l16 = lane & 15;
  int lq  = lane >> 4;

  floatx4 acc[4][4];
#pragma unroll
  for (int mi = 0; mi < 4; ++mi)
#pragma unroll
    for (int ni = 0; ni < 4; ++ni)
      acc[mi][ni] = (floatx4){0.f, 0.f, 0.f, 0.f};

  for (int k0 = 0; k0 < DIM; k0 += 32) {
    __syncthreads();
#pragma unroll
    for (int i = 0; i < 2; ++i) {
      int c = i * 256 + tid;
      int r = c >> 2;
      int col = (c & 3) << 3;
      int ra = bm + r; if (ra >= M) ra = M - 1;
      __builtin_amdgcn_global_load_lds(
          (const __attribute__((address_space(1))) void*)(A + (size_t)ra * DIM + k0 + col),
          (__attribute__((address_space(3))) void*)(As + c * 8), 16, 0, 0);
      __builtin_amdgcn_global_load_lds(
          (const __attribute__((address_space(1))) void*)(Bt + (size_t)(bn + r) * DIM + k0 + col),
          (__attribute__((address_space(3))) void*)(Bs + c * 8), 16, 0, 0);
    }
    __syncthreads();
    short8 av[4], bv[4];
#pragma unroll
    for (int mi = 0; mi < 4; ++mi)
      av[mi] = *(const short8*)&As[(wm + mi * 16 + l16) * 32 + lq * 8];
#pragma unroll
    for (int ni = 0; ni < 4; ++ni)
      bv[ni] = *(const short8*)&Bs[(wn + ni * 16 + l16) * 32 + lq * 8];
#pragma unroll
    for (int mi = 0; mi < 4; ++mi)
#pragma unroll
      for (int ni = 0; ni < 4; ++ni)
        acc[mi][ni] = __builtin_amdgcn_mfma_f32_16x16x32_bf16(av[mi], bv[ni], acc[mi][ni], 0, 0, 0);
  }

  // C/D layout: col = lane&15, row = (lane>>4)*4 + reg; emit fp8 e4m3 bytes
#pragma unroll
  for (int mi = 0; mi < 4; ++mi) {
#pragma unroll
    for (int r = 0; r < 4; ++r) {
      int row = bm + wm + mi * 16 + lq * 4 + r;
      if (row < M) {
#pragma unroll
        for (int ni = 0; ni < 4; ++ni) {
          float fv = acc[mi][ni][r];
          int pk = __builtin_amdgcn_cvt_pk_fp8_f32(fv, fv, 0, false);
          C8[(size_t)row * DIM + bn + wn + ni * 16 + l16] = (unsigned char)(pk & 0xff);
        }
      }
    }
  }
}

// ---------- attention scores from fp8 h ----------
template <int H>
__global__ __launch_bounds__(256)
void score_kernel(const unsigned char* __restrict__ h8,
                  const float* __restrict__ asrc, const float* __restrict__ adst,
                  float* __restrict__ ssrc, float* __restrict__ sdst) {
  constexpr int LPH = 48 / H;
  int wave = threadIdx.x >> 6, lane = threadIdx.x & 63;
  int n = blockIdx.x * 4 + wave;
  bool colane = lane < 48;
  int lc = min(lane, 47);
  int j = lc * 8;

  __shared__ float r1[4][64], r2[4][64];
  float s1 = 0.f, s2 = 0.f;
  if (colane) {
    uint2 pk = *(const uint2*)(h8 + (size_t)n * DIM + j);
    floatx2 p0 = __builtin_amdgcn_cvt_pk_f32_fp8((int)pk.x, false);
    floatx2 p1 = __builtin_amdgcn_cvt_pk_f32_fp8((int)pk.x, true);
    floatx2 p2 = __builtin_amdgcn_cvt_pk_f32_fp8((int)pk.y, false);
    floatx2 p3 = __builtin_amdgcn_cvt_pk_f32_fp8((int)pk.y, true);
    float f[8] = {p0.x, p0.y, p1.x, p1.y, p2.x, p2.y, p3.x, p3.y};
    float4 a0 = *(const float4*)(asrc + j);
    float4 a1 = *(const float4*)(asrc + j + 4);
    float4 d0 = *(const float4*)(adst + j);
    float4 d1 = *(const float4*)(adst + j + 4);
    s1 = f[0]*a0.x + f[1]*a0.y + f[2]*a0.z + f[3]*a0.w
       + f[4]*a1.x + f[5]*a1.y + f[6]*a1.z + f[7]*a1.w;
    s2 = f[0]*d0.x + f[1]*d0.y + f[2]*d0.z + f[3]*d0.w
       + f[4]*d1.x + f[5]*d1.y + f[6]*d1.z + f[7]*d1.w;
  }
  r1[wave][lane] = colane ? s1 : 0.f;
  r2[wave][lane] = colane ? s2 : 0.f;
  asm volatile("s_waitcnt lgkmcnt(0)" ::: "memory");
  __builtin_amdgcn_wave_barrier();
  if (lane < H) {
    float a = 0.f;
#pragma unroll
    for (int k = 0; k < LPH; ++k) a += r1[wave][lane * LPH + k];
    ssrc[n * H + lane] = a;
  } else if (lane >= 8 && lane < 8 + H) {
    int h = lane - 8;
    float a = 0.f;
#pragma unroll
    for (int k = 0; k < LPH; ++k) a += r2[wave][h * LPH + k];
    sdst[n * H + h] = a;
  }
}

// ---------- fused edge-softmax + weighted gather + epilogue ----------
// Neighbor indices preloaded into ONE per-lane register (srt row is contiguous):
// per batch, indices come from v_readlane/bpermute (no memory), so the only
// per-batch memory ops are the row gathers. Batches double-buffered (issue B,
// consume A) so one round-trip is in flight while the previous is consumed.
// w computed once per (edge,head) by lane slot*H+head, broadcast via __shfl.
// Max-free softmax (scores bounded); normalize by den at epilogue.
// MODE 0: outb = bf16(relu(LN(agg/den+bias)*g+be))
// MODE 1: outb = bf16(relu(agg/den+bias) + xresb)
template <int H, int MODE>
__global__ __launch_bounds__(128)
void aggregate_kernel(const int* __restrict__ row_ptr, const int* __restrict__ srt,
                      const float* __restrict__ ssrc, const float* __restrict__ sdst,
                      const unsigned char* __restrict__ h8, const float* __restrict__ bias,
                      const float* __restrict__ gamma, const float* __restrict__ beta,
                      const unsigned short* __restrict__ xresb,
                      unsigned short* __restrict__ outb) {
  constexpr int C = DIM / H;
  int wave = threadIdx.x >> 6;
  int lane = threadIdx.x & 63;
  int n = blockIdx.x * 2 + wave;
  int start = row_ptr[n];
  int deg = row_ptr[n + 1] - start;

  bool colane = lane < 48;
  int lc = min(lane, 47);
  int j = lc * 8;
  int myhead = j / C;

  // w-lane mapping: lane l computes w for edge-slot l/H, head l%H (clamped)
  int ww_i8 = min(lane / H, 7);
  int ww_i4 = min(lane / H, 3);
  int ww_h  = lane % H;

  float sd  = sdst[n * H + myhead];   // for scalar tails (this lane's head)
  float sdw = sdst[n * H + ww_h];     // for w-lane role

  float acc[8];
#pragma unroll
  for (int i = 0; i < 8; ++i) acc[i] = 0.f;
  float den = 0.f;

  const int* sp = srt + start;

  // preload whole neighbor list into one per-lane register (deg<=64 fast path)
  int myidx = sp[min(lane, deg - 1)];
  int fast = min(deg, 64);

  auto accum = [&](uint2 pk, float w) {
    floatx2 p0 = __builtin_amdgcn_cvt_pk_f32_fp8((int)pk.x, false);
    floatx2 p1 = __builtin_amdgcn_cvt_pk_f32_fp8((int)pk.x, true);
    floatx2 p2 = __builtin_amdgcn_cvt_pk_f32_fp8((int)pk.y, false);
    floatx2 p3 = __builtin_amdgcn_cvt_pk_f32_fp8((int)pk.y, true);
    acc[0] = fmaf(w, p0.x, acc[0]); acc[1] = fmaf(w, p0.y, acc[1]);
    acc[2] = fmaf(w, p1.x, acc[2]); acc[3] = fmaf(w, p1.y, acc[3]);
    acc[4] = fmaf(w, p2.x, acc[4]); acc[5] = fmaf(w, p2.y, acc[5]);
    acc[6] = fmaf(w, p3.x, acc[6]); acc[7] = fmaf(w, p3.y, acc[7]);
  };
  auto wexp = [&](float f) {
    float v = f + sdw;
    v = fmaxf(v, SLOPE * v);
    return __expf(v);
  };

  // issue: 1 ssrc gather (w-lanes) + 8 row gathers for batch at ee (reg indices)
  auto issue = [&](int ee, uint2 (&kk)[8], float& sv) {
    int msrc = __shfl(myidx, ee + ww_i8);
    sv = ssrc[msrc * H + ww_h];
#pragma unroll
    for (int i = 0; i < 8; ++i) {
      int si = __builtin_amdgcn_readlane(myidx, ee + i);
      kk[i] = *(const uint2*)(h8 + (size_t)si * DIM + j);
    }
  };
  auto consume = [&](uint2 (&kk)[8], float sv) {
    float wv = wexp(sv);
#pragma unroll
    for (int i = 0; i < 8; ++i) {
      float w = __shfl(wv, i * H + myhead);
      den += w;
      accum(kk[i], w);
    }
  };

  int ee = 0;
  int nb8 = fast >> 3;
  if (nb8 > 0) {
    uint2 kA[8], kB[8];
    float svA, svB;
    issue(0, kA, svA);
    int t = 1;
    for (; t + 1 < nb8; t += 2) {
      issue(t * 8, kB, svB);
      consume(kA, svA);
      issue((t + 1) * 8, kA, svA);
      consume(kB, svB);
    }
    if (t < nb8) {
      issue(t * 8, kB, svB);
      consume(kA, svA);
      consume(kB, svB);
    } else {
      consume(kA, svA);
    }
    ee = nb8 * 8;
  }
  if (ee + 4 <= fast) {
    int msrc = __shfl(myidx, ee + ww_i4);
    float sv = ssrc[msrc * H + ww_h];
    uint2 k[4];
#pragma unroll
    for (int i = 0; i < 4; ++i) {
      int si = __builtin_amdgcn_readlane(myidx, ee + i);
      k[i] = *(const uint2*)(h8 + (size_t)si * DIM + j);
    }
    float wv = wexp(sv);
#pragma unroll
    for (int i = 0; i < 4; ++i) {
      float w = __shfl(wv, i * H + myhead);
      den += w;
      accum(k[i], w);
    }
    ee += 4;
  }
  for (; ee < fast; ++ee) {
    int si = __builtin_amdgcn_readlane(myidx, ee);
    uint2 pk = *(const uint2*)(h8 + (size_t)si * DIM + j);
    float v = ssrc[si * H + myhead] + sd;
    v = fmaxf(v, SLOPE * v);
    float w = __expf(v);
    den += w;
    accum(pk, w);
  }
  // overflow path (deg > 64, rare): original memory-based serial loop
  for (; ee < deg; ++ee) {
    int su = __builtin_amdgcn_readfirstlane(sp[ee]);
    uint2 pk = *(const uint2*)(h8 + (size_t)su * DIM + j);
    float v = ssrc[su * H + myhead] + sd;
    v = fmaxf(v, SLOPE * v);
    float w = __expf(v);
    den += w;
    accum(pk, w);
  }

  // epilogue: normalize by denom, then bias + LN/residual
  float invden = 1.f / (den + 1e-16f);
  float v[8];
  float4 b0 = *(const float4*)(bias + j);
  float4 b1 = *(const float4*)(bias + j + 4);
  v[0] = acc[0] * invden + b0.x; v[1] = acc[1] * invden + b0.y;
  v[2] = acc[2] * invden + b0.z; v[3] = acc[3] * invden + b0.w;
  v[4] = acc[4] * invden + b1.x; v[5] = acc[5] * invden + b1.y;
  v[6] = acc[6] * invden + b1.z; v[7] = acc[7] * invden + b1.w;

  if (MODE == 0) {
    float s1 = 0.f, s2 = 0.f;
    if (colane) {
#pragma unroll
      for (int i = 0; i < 8; ++i) { s1 += v[i]; s2 += v[i] * v[i]; }
    }
#pragma unroll
    for (int off = 32; off > 0; off >>= 1) {
      s1 += __shfl_xor(s1, off);
      s2 += __shfl_xor(s2, off);
    }
    float mu = s1 * (1.f / DIM);
    float var = s2 * (1.f / DIM) - mu * mu;
    float rs = rsqrtf(var + LN_EPS);
    if (colane) {
      float4 g0 = *(const float4*)(gamma + j);
      float4 g1 = *(const float4*)(gamma + j + 4);
      float4 e0 = *(const float4*)(beta + j);
      float4 e1 = *(const float4*)(beta + j + 4);
      float gg[8] = {g0.x, g0.y, g0.z, g0.w, g1.x, g1.y, g1.z, g1.w};
      float bb[8] = {e0.x, e0.y, e0.z, e0.w, e1.x, e1.y, e1.z, e1.w};
      ushort4 o0, o1;
      unsigned short oy[8];
#pragma unroll
      for (int i = 0; i < 8; ++i) {
        float y = (v[i] - mu) * rs * gg[i] + bb[i];
        oy[i] = f2bf(fmaxf(y, 0.f));
      }
      o0.x = oy[0]; o0.y = oy[1]; o0.z = oy[2]; o0.w = oy[3];
      o1.x = oy[4]; o1.y = oy[5]; o1.z = oy[6]; o1.w = oy[7];
      *(ushort4*)(outb + (size_t)n * DIM + j) = o0;
      *(ushort4*)(outb + (size_t)n * DIM + j + 4) = o1;
    }
  } else {
    if (colane) {
      uint4 xp = *(const uint4*)(xresb + (size_t)n * DIM + j);
      float xf[8];
      xf[0] = __uint_as_float(xp.x << 16); xf[1] = __uint_as_float(xp.x & 0xffff0000u);
      xf[2] = __uint_as_float(xp.y << 16); xf[3] = __uint_as_float(xp.y & 0xffff0000u);
      xf[4] = __uint_as_float(xp.z << 16); xf[5] = __uint_as_float(xp.z & 0xffff0000u);
      xf[6] = __uint_as_float(xp.w << 16); xf[7] = __uint_as_float(xp.w & 0xffff0000u);
      ushort4 o0, o1;
      unsigned short oy[8];
#pragma unroll
      for (int i = 0; i < 8; ++i) oy[i] = f2bf(fmaxf(v[i], 0.f) + xf[i]);
      o0.x = oy[0]; o0.y = oy[1]; o0.z = oy[2]; o0.w = oy[3];
      o1.x = oy[4]; o1.y = oy[5]; o1.z = oy[6]; o1.w = oy[7];
      *(ushort4*)(outb + (size_t)n * DIM + j) = o0;
      *(ushort4*)(outb + (size_t)n * DIM + j + 4) = o1;
    }
  }
}

// ---------- global mean pool (bf16 input) ----------
__global__ void pool_kernel(const unsigned short* __restrict__ xr, const void* __restrict__ batch,
                            const int* __restrict__ flag, float* __restrict__ out) {
  int b = blockIdx.x;
  int s = blockIdx.y;
  int t = threadIdx.x;
  int is64 = *flag;
  int lo, hi;
  { int l = 0, r = NNODES;
    while (l < r) { int m = (l + r) >> 1; if (load_i(batch, m, is64) < b) l = m + 1; else r = m; }
    lo = l; }
  { int l = lo, r = NNODES;
    while (l < r) { int m = (l + r) >> 1; if (load_i(batch, m, is64) < b + 1) l = m + 1; else r = m; }
    hi = l; }
  int cnt = hi - lo;
  float inv = 1.f / (float)max(cnt, 1);
  int chunk = (cnt + POOLS - 1) / POOLS;
  int r0 = lo + s * chunk;
  int r1 = min(r0 + chunk, hi);
  float acc = 0.f;
  for (int nn = r0; nn < r1; ++nn) acc += bf2f(xr[(size_t)nn * DIM + t]);
  if (r1 > r0) atomicAdd(&out[b * DIM + t], acc * inv);
}

// ---------- launch ----------
extern "C" void kernel_launch(void* const* d_in, const int* in_sizes, int n_in,
                              void* d_out, int out_size, void* d_ws, size_t ws_size,
                              hipStream_t stream) {
  const float* x    = (const float*)d_in[0];
  const void*  ei   = d_in[1];
  const void*  batch= d_in[2];
  const float* W1   = (const float*)d_in[3];
  const float* a1s  = (const float*)d_in[4];
  const float* a1d  = (const float*)d_in[5];
  const float* b1   = (const float*)d_in[6];
  const float* g1   = (const float*)d_in[7];
  const float* be1  = (const float*)d_in[8];
  const float* W2   = (const float*)d_in[9];
  const float* a2s  = (const float*)d_in[10];
  const float* a2d  = (const float*)d_in[11];
  const float* b2   = (const float*)d_in[12];
  const float* g2   = (const float*)d_in[13];
  const float* be2  = (const float*)d_in[14];
  const float* W3   = (const float*)d_in[15];
  const float* a3s  = (const float*)d_in[16];
  const float* a3d  = (const float*)d_in[17];
  const float* b3   = (const float*)d_in[18];
  float* out = (float*)d_out;

  char* ws = (char*)d_ws;
  size_t off = 0;
  auto alloc = [&](size_t bytes) -> void* {
    void* p = ws + off;
    off = (off + bytes + 255) & ~(size_t)255;
    return p;
  };
  int*   flag    = (int*)alloc(4);
  unsigned short* Xb = (unsigned short*)alloc((size_t)NNODES * DIM * 2);
  unsigned short* Qb = (unsigned short*)alloc((size_t)NNODES * DIM * 2);
  unsigned char*  P8 = (unsigned char*)alloc((size_t)NNODES * DIM);
  unsigned short* Wt = (unsigned short*)alloc((size_t)3 * DIM * DIM * 2);
  float* ssrc    = (float*)alloc((size_t)NNODES * 6 * 4);
  float* sdst    = (float*)alloc((size_t)NNODES * 6 * 4);
  int*   row_ptr = (int*)alloc((size_t)(NNODES + 1) * 4);
  int*   cursor  = (int*)alloc((size_t)NNODES * 4);
  int*   deg     = (int*)alloc((size_t)NNODES * 4);
  int*   btot    = (int*)alloc((size_t)NSCB * 4);
  int*   srt     = (int*)alloc((size_t)EPRIME * 4);

  detect_kernel<<<1, 256, 0, stream>>>((const int*)ei, flag);
  hipMemsetAsync(deg, 0, (size_t)NNODES * 4, stream);
  hipMemsetAsync(d_out, 0, (size_t)out_size * 4, stream);
  int eblocks = (EPRIME + 255) / 256;
  count_kernel<<<eblocks, 256, 0, stream>>>(ei, flag, deg);
  scan1_kernel<<<NSCB, SCANB, 0, stream>>>(deg, row_ptr, btot);
  scan2_kernel<<<1, 256, 0, stream>>>(btot);
  scan3_kernel<<<NSCB, SCANB, 0, stream>>>(row_ptr, cursor, btot);
  scatter_kernel<<<eblocks, 256, 0, stream>>>(ei, flag, cursor, srt);

  convert_x_kernel<<<(NNODES * DIM / 4 + 255) / 256, 256, 0, stream>>>(x, Xb);
  convert_w_kernel<<<dim3(DIM, 3), DIM, 0, stream>>>(W1, W2, W3, Wt);

  dim3 ggrid((NNODES + 127) / 128, DIM / 128);
  int agrid = NNODES / 2;

  // layer 1
  gemm_bf16_kernel<<<ggrid, 256, 0, stream>>>(Xb, Wt, P8, NNODES);
  score_kernel<4><<<NNODES / 4, 256, 0, stream>>>(P8, a1s, a1d, ssrc, sdst);
  aggregate_kernel<4, 0><<<agrid, 128, 0, stream>>>(row_ptr, srt, ssrc, sdst, P8, b1, g1, be1,
                                                    nullptr, Qb);
  // layer 2
  gemm_bf16_kernel<<<ggrid, 256, 0, stream>>>(Qb, Wt + (size_t)DIM * DIM, P8, NNODES);
  score_kernel<4><<<NNODES / 4, 256, 0, stream>>>(P8, a2s, a2d, ssrc, sdst);
  aggregate_kernel<4, 0><<<agrid, 128, 0, stream>>>(row_ptr, srt, ssrc, sdst, P8, b2, g2, be2,
                                                    nullptr, Qb);
  // layer 3 (bf16 residual fused; output overwrites Qb)
  gemm_bf16_kernel<<<ggrid, 256, 0, stream>>>(Qb, Wt + (size_t)2 * DIM * DIM, P8, NNODES);
  score_kernel<6><<<NNODES / 4, 256, 0, stream>>>(P8, a3s, a3d, ssrc, sdst);
  aggregate_kernel<6, 1><<<agrid, 128, 0, stream>>>(row_ptr, srt, ssrc, sdst, P8, b3, nullptr,
                                                    nullptr, Xb, Qb);
  // mean pool (bf16 input)
  pool_kernel<<<dim3(NB, POOLS), DIM, 0, stream>>>(Qb, batch, flag, out);
}

// Round 7
// 511.638 us; speedup vs baseline: 1.0774x; 1.0774x over previous
//
#include <hip/hip_runtime.h>

#define NNODES 50000
#define NEDGES 500000
#define DIM    384
#define NB     64
#define SLOPE  0.2f
#define LN_EPS 1e-5f
#define EPRIME (NEDGES + NNODES)
#define POOLS  16
#define SCANB  256
#define NSCB   ((NNODES + SCANB - 1) / SCANB)   // 196

typedef __attribute__((ext_vector_type(8))) short short8;
typedef __attribute__((ext_vector_type(4))) float floatx4;
typedef __attribute__((ext_vector_type(2))) float floatx2;

// ---------- helpers ----------
__device__ __forceinline__ int load_i(const void* p, long long i, int is64) {
  return is64 ? (int)((const long long*)p)[i] : ((const int*)p)[i];
}
__device__ __forceinline__ unsigned short f2bf(float f) {
  unsigned u = __float_as_uint(f);
  u += 0x7fffu + ((u >> 16) & 1u);
  return (unsigned short)(u >> 16);
}
__device__ __forceinline__ float bf2f(unsigned short u) {
  return __uint_as_float(((unsigned)u) << 16);
}

// ---------- dtype detect (int64 vs int32) ----------
__global__ void detect_kernel(const int* __restrict__ ei32, int* __restrict__ flag) {
  __shared__ int nz;
  if (threadIdx.x == 0) nz = 0;
  __syncthreads();
  if (ei32[2 * threadIdx.x + 1] != 0) atomicAdd(&nz, 1);
  __syncthreads();
  if (threadIdx.x == 0) *flag = (nz == 0) ? 1 : 0;
}

// ---------- CSR build ----------
__global__ void count_kernel(const void* __restrict__ ei, const int* __restrict__ flag,
                             int* __restrict__ deg) {
  int is64 = *flag;
  for (int i = blockIdx.x * blockDim.x + threadIdx.x; i < EPRIME; i += gridDim.x * blockDim.x) {
    int d = (i < NEDGES) ? load_i(ei, (long long)NEDGES + i, is64) : (i - NEDGES);
    atomicAdd(&deg[d], 1);
  }
}

__global__ void scan1_kernel(const int* __restrict__ deg, int* __restrict__ row_ptr,
                             int* __restrict__ btot) {
  __shared__ int buf[SCANB];
  int t = threadIdx.x, idx = blockIdx.x * SCANB + t;
  int v = (idx < NNODES) ? deg[idx] : 0;
  buf[t] = v;
  __syncthreads();
  for (int off = 1; off < SCANB; off <<= 1) {
    int x = (t >= off) ? buf[t - off] : 0;
    __syncthreads();
    buf[t] += x;
    __syncthreads();
  }
  if (idx < NNODES) row_ptr[idx] = buf[t] - v;
  if (t == SCANB - 1) btot[blockIdx.x] = buf[t];
}
__global__ void scan2_kernel(int* __restrict__ btot) {
  __shared__ int buf[256];
  int t = threadIdx.x;
  int v = (t < NSCB) ? btot[t] : 0;
  buf[t] = v;
  __syncthreads();
  for (int off = 1; off < 256; off <<= 1) {
    int x = (t >= off) ? buf[t - off] : 0;
    __syncthreads();
    buf[t] += x;
    __syncthreads();
  }
  if (t < NSCB) btot[t] = buf[t] - v;
}
__global__ void scan3_kernel(int* __restrict__ row_ptr, int* __restrict__ cursor,
                             const int* __restrict__ btot) {
  int idx = blockIdx.x * SCANB + threadIdx.x;
  if (idx < NNODES) {
    int v = row_ptr[idx] + btot[blockIdx.x];
    row_ptr[idx] = v;
    cursor[idx] = v;
  }
  if (idx == 0) row_ptr[NNODES] = EPRIME;
}

__global__ void scatter_kernel(const void* __restrict__ ei, const int* __restrict__ flag,
                               int* __restrict__ cursor, int* __restrict__ srt,
                               int* __restrict__ dstE) {
  int is64 = *flag;
  for (int i = blockIdx.x * blockDim.x + threadIdx.x; i < EPRIME; i += gridDim.x * blockDim.x) {
    int s, d;
    if (i < NEDGES) { s = load_i(ei, i, is64); d = load_i(ei, (long long)NEDGES + i, is64); }
    else            { s = d = i - NEDGES; }
    int pos = atomicAdd(&cursor[d], 1);
    srt[pos] = s;
    dstE[pos] = d;
  }
}

// ---------- conversions ----------
__global__ void convert_x_kernel(const float* __restrict__ x, unsigned short* __restrict__ xb) {
  int i = blockIdx.x * blockDim.x + threadIdx.x;
  float4 v = ((const float4*)x)[i];
  ushort4 o;
  o.x = f2bf(v.x); o.y = f2bf(v.y); o.z = f2bf(v.z); o.w = f2bf(v.w);
  ((ushort4*)xb)[i] = o;
}

__global__ void convert_w_kernel(const float* __restrict__ W1, const float* __restrict__ W2,
                                 const float* __restrict__ W3, unsigned short* __restrict__ Wt) {
  const float* W = (blockIdx.y == 0) ? W1 : (blockIdx.y == 1) ? W2 : W3;
  unsigned short* o = Wt + (size_t)blockIdx.y * DIM * DIM;
  int n = blockIdx.x;
  int k = threadIdx.x;
  o[n * DIM + k] = f2bf(W[k * DIM + n]);
}

// ---------- bf16 MFMA GEMM -> fp8 e4m3 output (h only ever consumed as fp8) ----------
__global__ __launch_bounds__(256)
void gemm_bf16_kernel(const unsigned short* __restrict__ A,
                      const unsigned short* __restrict__ Bt,
                      unsigned char* __restrict__ C8, int M) {
  __shared__ unsigned short As[128 * 32];
  __shared__ unsigned short Bs[128 * 32];
  int tid = threadIdx.x;
  int lane = tid & 63;
  int wave = tid >> 6;
  int bm = blockIdx.x * 128;
  int bn = blockIdx.y * 128;
  int wm = (wave & 1) * 64;
  int wn = (wave >> 1) * 64;
  int l16 = lane & 15;
  int lq  = lane >> 4;

  floatx4 acc[4][4];
#pragma unroll
  for (int mi = 0; mi < 4; ++mi)
#pragma unroll
    for (int ni = 0; ni < 4; ++ni)
      acc[mi][ni] = (floatx4){0.f, 0.f, 0.f, 0.f};

  for (int k0 = 0; k0 < DIM; k0 += 32) {
    __syncthreads();
#pragma unroll
    for (int i = 0; i < 2; ++i) {
      int c = i * 256 + tid;
      int r = c >> 2;
      int col = (c & 3) << 3;
      int ra = bm + r; if (ra >= M) ra = M - 1;
      __builtin_amdgcn_global_load_lds(
          (const __attribute__((address_space(1))) void*)(A + (size_t)ra * DIM + k0 + col),
          (__attribute__((address_space(3))) void*)(As + c * 8), 16, 0, 0);
      __builtin_amdgcn_global_load_lds(
          (const __attribute__((address_space(1))) void*)(Bt + (size_t)(bn + r) * DIM + k0 + col),
          (__attribute__((address_space(3))) void*)(Bs + c * 8), 16, 0, 0);
    }
    __syncthreads();
    short8 av[4], bv[4];
#pragma unroll
    for (int mi = 0; mi < 4; ++mi)
      av[mi] = *(const short8*)&As[(wm + mi * 16 + l16) * 32 + lq * 8];
#pragma unroll
    for (int ni = 0; ni < 4; ++ni)
      bv[ni] = *(const short8*)&Bs[(wn + ni * 16 + l16) * 32 + lq * 8];
#pragma unroll
    for (int mi = 0; mi < 4; ++mi)
#pragma unroll
      for (int ni = 0; ni < 4; ++ni)
        acc[mi][ni] = __builtin_amdgcn_mfma_f32_16x16x32_bf16(av[mi], bv[ni], acc[mi][ni], 0, 0, 0);
  }

  // C/D layout: col = lane&15, row = (lane>>4)*4 + reg; emit fp8 e4m3 bytes
#pragma unroll
  for (int mi = 0; mi < 4; ++mi) {
#pragma unroll
    for (int r = 0; r < 4; ++r) {
      int row = bm + wm + mi * 16 + lq * 4 + r;
      if (row < M) {
#pragma unroll
        for (int ni = 0; ni < 4; ++ni) {
          float fv = acc[mi][ni][r];
          int pk = __builtin_amdgcn_cvt_pk_fp8_f32(fv, fv, 0, false);
          C8[(size_t)row * DIM + bn + wn + ni * 16 + l16] = (unsigned char)(pk & 0xff);
        }
      }
    }
  }
}

// ---------- attention scores from fp8 h ----------
template <int H>
__global__ __launch_bounds__(256)
void score_kernel(const unsigned char* __restrict__ h8,
                  const float* __restrict__ asrc, const float* __restrict__ adst,
                  float* __restrict__ ssrc, float* __restrict__ sdst) {
  constexpr int LPH = 48 / H;
  int wave = threadIdx.x >> 6, lane = threadIdx.x & 63;
  int n = blockIdx.x * 4 + wave;
  bool colane = lane < 48;
  int lc = min(lane, 47);
  int j = lc * 8;

  __shared__ float r1[4][64], r2[4][64];
  float s1 = 0.f, s2 = 0.f;
  if (colane) {
    uint2 pk = *(const uint2*)(h8 + (size_t)n * DIM + j);
    floatx2 p0 = __builtin_amdgcn_cvt_pk_f32_fp8((int)pk.x, false);
    floatx2 p1 = __builtin_amdgcn_cvt_pk_f32_fp8((int)pk.x, true);
    floatx2 p2 = __builtin_amdgcn_cvt_pk_f32_fp8((int)pk.y, false);
    floatx2 p3 = __builtin_amdgcn_cvt_pk_f32_fp8((int)pk.y, true);
    float f[8] = {p0.x, p0.y, p1.x, p1.y, p2.x, p2.y, p3.x, p3.y};
    float4 a0 = *(const float4*)(asrc + j);
    float4 a1 = *(const float4*)(asrc + j + 4);
    float4 d0 = *(const float4*)(adst + j);
    float4 d1 = *(const float4*)(adst + j + 4);
    s1 = f[0]*a0.x + f[1]*a0.y + f[2]*a0.z + f[3]*a0.w
       + f[4]*a1.x + f[5]*a1.y + f[6]*a1.z + f[7]*a1.w;
    s2 = f[0]*d0.x + f[1]*d0.y + f[2]*d0.z + f[3]*d0.w
       + f[4]*d1.x + f[5]*d1.y + f[6]*d1.z + f[7]*d1.w;
  }
  r1[wave][lane] = colane ? s1 : 0.f;
  r2[wave][lane] = colane ? s2 : 0.f;
  asm volatile("s_waitcnt lgkmcnt(0)" ::: "memory");
  __builtin_amdgcn_wave_barrier();
  if (lane < H) {
    float a = 0.f;
#pragma unroll
    for (int k = 0; k < LPH; ++k) a += r1[wave][lane * LPH + k];
    ssrc[n * H + lane] = a;
  } else if (lane >= 8 && lane < 8 + H) {
    int h = lane - 8;
    float a = 0.f;
#pragma unroll
    for (int k = 0; k < LPH; ++k) a += r2[wave][h * LPH + k];
    sdst[n * H + h] = a;
  }
}

// ---------- edge-parallel unnormalized weights ----------
// One thread per CSR slot: w = exp(leaky(ssrc[src]+sdst[dst])). ssrc/sdst are
// L2-resident (<=1.2 MB); 550k independent threads — no serial chain.
template <int H>
__global__ __launch_bounds__(256)
void wexp_edge_kernel(const int* __restrict__ srt, const int* __restrict__ dstE,
                      const float* __restrict__ ssrc, const float* __restrict__ sdst,
                      float* __restrict__ walpha) {
  int i = blockIdx.x * 256 + threadIdx.x;
  if (i >= EPRIME) return;
  int s = srt[i];
  int d = dstE[i];
  auto wfun = [](float v) {
    v = fmaxf(v, SLOPE * v);
    return __expf(v);
  };
  if (H == 4) {
    float4 a = *(const float4*)(ssrc + (size_t)s * 4);
    float4 b = *(const float4*)(sdst + (size_t)d * 4);
    float4 o;
    o.x = wfun(a.x + b.x);
    o.y = wfun(a.y + b.y);
    o.z = wfun(a.z + b.z);
    o.w = wfun(a.w + b.w);
    *(float4*)(walpha + (size_t)i * 4) = o;
  } else {
    const floatx2* pa = (const floatx2*)(ssrc + (size_t)s * 6);
    const floatx2* pb = (const floatx2*)(sdst + (size_t)d * 6);
    floatx2* po = (floatx2*)(walpha + (size_t)i * 6);
#pragma unroll
    for (int k = 0; k < 3; ++k) {
      floatx2 a = pa[k], b = pb[k];
      floatx2 o;
      o.x = wfun(a.x + b.x);
      o.y = wfun(a.y + b.y);
      po[k] = o;
    }
  }
}

// ---------- pure weighted gather + fused epilogue (R0 core, 32 VGPR) ----------
// den accumulated inline from the linear walpha stream in the SAME edge order
// the old wexp used -> bit-identical numerics, dden buffer/read eliminated.
// MODE 0: outb = bf16(relu(LN(agg/den+bias)*g+be))
// MODE 1: outb = bf16(relu(agg/den+bias) + xresb)
template <int H, int MODE>
__global__ __launch_bounds__(256)
void aggregate_kernel(const int* __restrict__ row_ptr, const int* __restrict__ srt,
                      const float* __restrict__ walpha,
                      const unsigned char* __restrict__ h8, const float* __restrict__ bias,
                      const float* __restrict__ gamma, const float* __restrict__ beta,
                      const unsigned short* __restrict__ xresb,
                      unsigned short* __restrict__ outb) {
  constexpr int C = DIM / H;
  int wave = threadIdx.x >> 6;
  int lane = threadIdx.x & 63;
  int n = blockIdx.x * 4 + wave;
  int start = row_ptr[n];
  int deg = row_ptr[n + 1] - start;

  bool colane = lane < 48;
  int lc = min(lane, 47);
  int j = lc * 8;
  int myhead = j / C;

  float acc[8];
#pragma unroll
  for (int i = 0; i < 8; ++i) acc[i] = 0.f;
  float den = 0.f;

  const int* sp = srt + start;
  const float* ap = walpha + (size_t)start * H + myhead;

  auto accum = [&](uint2 pk, float w) {
    floatx2 p0 = __builtin_amdgcn_cvt_pk_f32_fp8((int)pk.x, false);
    floatx2 p1 = __builtin_amdgcn_cvt_pk_f32_fp8((int)pk.x, true);
    floatx2 p2 = __builtin_amdgcn_cvt_pk_f32_fp8((int)pk.y, false);
    floatx2 p3 = __builtin_amdgcn_cvt_pk_f32_fp8((int)pk.y, true);
    acc[0] = fmaf(w, p0.x, acc[0]); acc[1] = fmaf(w, p0.y, acc[1]);
    acc[2] = fmaf(w, p1.x, acc[2]); acc[3] = fmaf(w, p1.y, acc[3]);
    acc[4] = fmaf(w, p2.x, acc[4]); acc[5] = fmaf(w, p2.y, acc[5]);
    acc[6] = fmaf(w, p3.x, acc[6]); acc[7] = fmaf(w, p3.y, acc[7]);
  };

  int ee = 0;
  for (; ee + 4 <= deg; ee += 4) {
    int i0 = sp[ee], i1 = sp[ee + 1], i2 = sp[ee + 2], i3 = sp[ee + 3];
    int s0 = __builtin_amdgcn_readfirstlane(i0);
    int s1 = __builtin_amdgcn_readfirstlane(i1);
    int s2 = __builtin_amdgcn_readfirstlane(i2);
    int s3 = __builtin_amdgcn_readfirstlane(i3);
    uint2 k0 = *(const uint2*)(h8 + (size_t)s0 * DIM + j);
    uint2 k1 = *(const uint2*)(h8 + (size_t)s1 * DIM + j);
    uint2 k2 = *(const uint2*)(h8 + (size_t)s2 * DIM + j);
    uint2 k3 = *(const uint2*)(h8 + (size_t)s3 * DIM + j);
    float w0 = ap[(ee) * H];
    float w1 = ap[(ee + 1) * H];
    float w2 = ap[(ee + 2) * H];
    float w3 = ap[(ee + 3) * H];
    den += w0; den += w1; den += w2; den += w3;
    accum(k0, w0); accum(k1, w1); accum(k2, w2); accum(k3, w3);
  }
  for (; ee < deg; ++ee) {
    int su = __builtin_amdgcn_readfirstlane(sp[ee]);
    uint2 pk = *(const uint2*)(h8 + (size_t)su * DIM + j);
    float w = ap[ee * H];
    den += w;
    accum(pk, w);
  }

  // epilogue: normalize by denom, then bias + LN/residual
  float invden = 1.f / (den + 1e-16f);
  float v[8];
  float4 b0 = *(const float4*)(bias + j);
  float4 b1 = *(const float4*)(bias + j + 4);
  v[0] = acc[0] * invden + b0.x; v[1] = acc[1] * invden + b0.y;
  v[2] = acc[2] * invden + b0.z; v[3] = acc[3] * invden + b0.w;
  v[4] = acc[4] * invden + b1.x; v[5] = acc[5] * invden + b1.y;
  v[6] = acc[6] * invden + b1.z; v[7] = acc[7] * invden + b1.w;

  if (MODE == 0) {
    float s1 = 0.f, s2 = 0.f;
    if (colane) {
#pragma unroll
      for (int i = 0; i < 8; ++i) { s1 += v[i]; s2 += v[i] * v[i]; }
    }
#pragma unroll
    for (int off = 32; off > 0; off >>= 1) {
      s1 += __shfl_xor(s1, off);
      s2 += __shfl_xor(s2, off);
    }
    float mu = s1 * (1.f / DIM);
    float var = s2 * (1.f / DIM) - mu * mu;
    float rs = rsqrtf(var + LN_EPS);
    if (colane) {
      float4 g0 = *(const float4*)(gamma + j);
      float4 g1 = *(const float4*)(gamma + j + 4);
      float4 e0 = *(const float4*)(beta + j);
      float4 e1 = *(const float4*)(beta + j + 4);
      float gg[8] = {g0.x, g0.y, g0.z, g0.w, g1.x, g1.y, g1.z, g1.w};
      float bb[8] = {e0.x, e0.y, e0.z, e0.w, e1.x, e1.y, e1.z, e1.w};
      ushort4 o0, o1;
      unsigned short oy[8];
#pragma unroll
      for (int i = 0; i < 8; ++i) {
        float y = (v[i] - mu) * rs * gg[i] + bb[i];
        oy[i] = f2bf(fmaxf(y, 0.f));
      }
      o0.x = oy[0]; o0.y = oy[1]; o0.z = oy[2]; o0.w = oy[3];
      o1.x = oy[4]; o1.y = oy[5]; o1.z = oy[6]; o1.w = oy[7];
      *(ushort4*)(outb + (size_t)n * DIM + j) = o0;
      *(ushort4*)(outb + (size_t)n * DIM + j + 4) = o1;
    }
  } else {
    if (colane) {
      uint4 xp = *(const uint4*)(xresb + (size_t)n * DIM + j);
      float xf[8];
      xf[0] = __uint_as_float(xp.x << 16); xf[1] = __uint_as_float(xp.x & 0xffff0000u);
      xf[2] = __uint_as_float(xp.y << 16); xf[3] = __uint_as_float(xp.y & 0xffff0000u);
      xf[4] = __uint_as_float(xp.z << 16); xf[5] = __uint_as_float(xp.z & 0xffff0000u);
      xf[6] = __uint_as_float(xp.w << 16); xf[7] = __uint_as_float(xp.w & 0xffff0000u);
      ushort4 o0, o1;
      unsigned short oy[8];
#pragma unroll
      for (int i = 0; i < 8; ++i) oy[i] = f2bf(fmaxf(v[i], 0.f) + xf[i]);
      o0.x = oy[0]; o0.y = oy[1]; o0.z = oy[2]; o0.w = oy[3];
      o1.x = oy[4]; o1.y = oy[5]; o1.z = oy[6]; o1.w = oy[7];
      *(ushort4*)(outb + (size_t)n * DIM + j) = o0;
      *(ushort4*)(outb + (size_t)n * DIM + j + 4) = o1;
    }
  }
}

// ---------- global mean pool (bf16 input) ----------
__global__ void pool_kernel(const unsigned short* __restrict__ xr, const void* __restrict__ batch,
                            const int* __restrict__ flag, float* __restrict__ out) {
  int b = blockIdx.x;
  int s = blockIdx.y;
  int t = threadIdx.x;
  int is64 = *flag;
  int lo, hi;
  { int l = 0, r = NNODES;
    while (l < r) { int m = (l + r) >> 1; if (load_i(batch, m, is64) < b) l = m + 1; else r = m; }
    lo = l; }
  { int l = lo, r = NNODES;
    while (l < r) { int m = (l + r) >> 1; if (load_i(batch, m, is64) < b + 1) l = m + 1; else r = m; }
    hi = l; }
  int cnt = hi - lo;
  float inv = 1.f / (float)max(cnt, 1);
  int chunk = (cnt + POOLS - 1) / POOLS;
  int r0 = lo + s * chunk;
  int r1 = min(r0 + chunk, hi);
  float acc = 0.f;
  for (int nn = r0; nn < r1; ++nn) acc += bf2f(xr[(size_t)nn * DIM + t]);
  if (r1 > r0) atomicAdd(&out[b * DIM + t], acc * inv);
}

// ---------- launch ----------
extern "C" void kernel_launch(void* const* d_in, const int* in_sizes, int n_in,
                              void* d_out, int out_size, void* d_ws, size_t ws_size,
                              hipStream_t stream) {
  const float* x    = (const float*)d_in[0];
  const void*  ei   = d_in[1];
  const void*  batch= d_in[2];
  const float* W1   = (const float*)d_in[3];
  const float* a1s  = (const float*)d_in[4];
  const float* a1d  = (const float*)d_in[5];
  const float* b1   = (const float*)d_in[6];
  const float* g1   = (const float*)d_in[7];
  const float* be1  = (const float*)d_in[8];
  const float* W2   = (const float*)d_in[9];
  const float* a2s  = (const float*)d_in[10];
  const float* a2d  = (const float*)d_in[11];
  const float* b2   = (const float*)d_in[12];
  const float* g2   = (const float*)d_in[13];
  const float* be2  = (const float*)d_in[14];
  const float* W3   = (const float*)d_in[15];
  const float* a3s  = (const float*)d_in[16];
  const float* a3d  = (const float*)d_in[17];
  const float* b3   = (const float*)d_in[18];
  float* out = (float*)d_out;

  char* ws = (char*)d_ws;
  size_t off = 0;
  auto alloc = [&](size_t bytes) -> void* {
    void* p = ws + off;
    off = (off + bytes + 255) & ~(size_t)255;
    return p;
  };
  int*   flag    = (int*)alloc(4);
  unsigned short* Xb = (unsigned short*)alloc((size_t)NNODES * DIM * 2);
  unsigned short* Qb = (unsigned short*)alloc((size_t)NNODES * DIM * 2);
  unsigned char*  P8 = (unsigned char*)alloc((size_t)NNODES * DIM);
  unsigned short* Wt = (unsigned short*)alloc((size_t)3 * DIM * DIM * 2);
  float* ssrc    = (float*)alloc((size_t)NNODES * 6 * 4);
  float* sdst    = (float*)alloc((size_t)NNODES * 6 * 4);
  float* walpha  = (float*)alloc((size_t)EPRIME * 6 * 4);
  int*   row_ptr = (int*)alloc((size_t)(NNODES + 1) * 4);
  int*   cursor  = (int*)alloc((size_t)NNODES * 4);
  int*   deg     = (int*)alloc((size_t)NNODES * 4);
  int*   btot    = (int*)alloc((size_t)NSCB * 4);
  int*   srt     = (int*)alloc((size_t)EPRIME * 4);
  int*   dstE    = (int*)alloc((size_t)EPRIME * 4);

  detect_kernel<<<1, 256, 0, stream>>>((const int*)ei, flag);
  hipMemsetAsync(deg, 0, (size_t)NNODES * 4, stream);
  hipMemsetAsync(d_out, 0, (size_t)out_size * 4, stream);
  int eblocks = (EPRIME + 255) / 256;
  count_kernel<<<eblocks, 256, 0, stream>>>(ei, flag, deg);
  scan1_kernel<<<NSCB, SCANB, 0, stream>>>(deg, row_ptr, btot);
  scan2_kernel<<<1, 256, 0, stream>>>(btot);
  scan3_kernel<<<NSCB, SCANB, 0, stream>>>(row_ptr, cursor, btot);
  scatter_kernel<<<eblocks, 256, 0, stream>>>(ei, flag, cursor, srt, dstE);

  convert_x_kernel<<<(NNODES * DIM / 4 + 255) / 256, 256, 0, stream>>>(x, Xb);
  convert_w_kernel<<<dim3(DIM, 3), DIM, 0, stream>>>(W1, W2, W3, Wt);

  dim3 ggrid((NNODES + 127) / 128, DIM / 128);
  int agrid = NNODES / 4;

  // layer 1
  gemm_bf16_kernel<<<ggrid, 256, 0, stream>>>(Xb, Wt, P8, NNODES);
  score_kernel<4><<<agrid, 256, 0, stream>>>(P8, a1s, a1d, ssrc, sdst);
  wexp_edge_kernel<4><<<eblocks, 256, 0, stream>>>(srt, dstE, ssrc, sdst, walpha);
  aggregate_kernel<4, 0><<<agrid, 256, 0, stream>>>(row_ptr, srt, walpha, P8, b1, g1, be1,
                                                    nullptr, Qb);
  // layer 2
  gemm_bf16_kernel<<<ggrid, 256, 0, stream>>>(Qb, Wt + (size_t)DIM * DIM, P8, NNODES);
  score_kernel<4><<<agrid, 256, 0, stream>>>(P8, a2s, a2d, ssrc, sdst);
  wexp_edge_kernel<4><<<eblocks, 256, 0, stream>>>(srt, dstE, ssrc, sdst, walpha);
  aggregate_kernel<4, 0><<<agrid, 256, 0, stream>>>(row_ptr, srt, walpha, P8, b2, g2, be2,
                                                    nullptr, Qb);
  // layer 3 (bf16 residual fused; output overwrites Qb)
  gemm_bf16_kernel<<<ggrid, 256, 0, stream>>>(Qb, Wt + (size_t)2 * DIM * DIM, P8, NNODES);
  score_kernel<6><<<agrid, 256, 0, stream>>>(P8, a3s, a3d, ssrc, sdst);
  wexp_edge_kernel<6><<<eblocks, 256, 0, stream>>>(srt, dstE, ssrc, sdst, walpha);
  aggregate_kernel<6, 1><<<agrid, 256, 0, stream>>>(row_ptr, srt, walpha, P8, b3, nullptr,
                                                    nullptr, Xb, Qb);
  // mean pool (bf16 input)
  pool_kernel<<<dim3(NB, POOLS), DIM, 0, stream>>>(Qb, batch, flag, out);
}

// Round 9
// 502.733 us; speedup vs baseline: 1.0965x; 1.0177x over previous
//
#include <hip/hip_runtime.h>

#define NNODES 50000
#define NEDGES 500000
#define DIM    384
#define NB     64
#define SLOPE  0.2f
#define LN_EPS 1e-5f
#define EPRIME (NEDGES + NNODES)
#define POOLS  16
#define SCANB  256
#define NSCB   ((NNODES + SCANB - 1) / SCANB)   // 196

typedef __attribute__((ext_vector_type(8))) short short8;
typedef __attribute__((ext_vector_type(4))) float floatx4;
typedef __attribute__((ext_vector_type(2))) float floatx2;

// ---------- helpers ----------
__device__ __forceinline__ int load_i(const void* p, long long i, int is64) {
  return is64 ? (int)((const long long*)p)[i] : ((const int*)p)[i];
}
__device__ __forceinline__ unsigned short f2bf(float f) {
  unsigned u = __float_as_uint(f);
  u += 0x7fffu + ((u >> 16) & 1u);
  return (unsigned short)(u >> 16);
}
__device__ __forceinline__ float bf2f(unsigned short u) {
  return __uint_as_float(((unsigned)u) << 16);
}

// ---------- dtype detect (int64 vs int32) ----------
__global__ void detect_kernel(const int* __restrict__ ei32, int* __restrict__ flag) {
  __shared__ int nz;
  if (threadIdx.x == 0) nz = 0;
  __syncthreads();
  if (ei32[2 * threadIdx.x + 1] != 0) atomicAdd(&nz, 1);
  __syncthreads();
  if (threadIdx.x == 0) *flag = (nz == 0) ? 1 : 0;
}

// ---------- CSR build ----------
__global__ void count_kernel(const void* __restrict__ ei, const int* __restrict__ flag,
                             int* __restrict__ deg) {
  int is64 = *flag;
  for (int i = blockIdx.x * blockDim.x + threadIdx.x; i < EPRIME; i += gridDim.x * blockDim.x) {
    int d = (i < NEDGES) ? load_i(ei, (long long)NEDGES + i, is64) : (i - NEDGES);
    atomicAdd(&deg[d], 1);
  }
}

__global__ void scan1_kernel(const int* __restrict__ deg, int* __restrict__ row_ptr,
                             int* __restrict__ btot) {
  __shared__ int buf[SCANB];
  int t = threadIdx.x, idx = blockIdx.x * SCANB + t;
  int v = (idx < NNODES) ? deg[idx] : 0;
  buf[t] = v;
  __syncthreads();
  for (int off = 1; off < SCANB; off <<= 1) {
    int x = (t >= off) ? buf[t - off] : 0;
    __syncthreads();
    buf[t] += x;
    __syncthreads();
  }
  if (idx < NNODES) row_ptr[idx] = buf[t] - v;
  if (t == SCANB - 1) btot[blockIdx.x] = buf[t];
}
__global__ void scan2_kernel(int* __restrict__ btot) {
  __shared__ int buf[256];
  int t = threadIdx.x;
  int v = (t < NSCB) ? btot[t] : 0;
  buf[t] = v;
  __syncthreads();
  for (int off = 1; off < 256; off <<= 1) {
    int x = (t >= off) ? buf[t - off] : 0;
    __syncthreads();
    buf[t] += x;
    __syncthreads();
  }
  if (t < NSCB) btot[t] = buf[t] - v;
}
__global__ void scan3_kernel(int* __restrict__ row_ptr, int* __restrict__ cursor,
                             const int* __restrict__ btot) {
  int idx = blockIdx.x * SCANB + threadIdx.x;
  if (idx < NNODES) {
    int v = row_ptr[idx] + btot[blockIdx.x];
    row_ptr[idx] = v;
    cursor[idx] = v;
  }
  if (idx == 0) row_ptr[NNODES] = EPRIME;
}

__global__ void scatter_kernel(const void* __restrict__ ei, const int* __restrict__ flag,
                               int* __restrict__ cursor, int* __restrict__ srt,
                               int* __restrict__ dstE) {
  int is64 = *flag;
  for (int i = blockIdx.x * blockDim.x + threadIdx.x; i < EPRIME; i += gridDim.x * blockDim.x) {
    int s, d;
    if (i < NEDGES) { s = load_i(ei, i, is64); d = load_i(ei, (long long)NEDGES + i, is64); }
    else            { s = d = i - NEDGES; }
    int pos = atomicAdd(&cursor[d], 1);
    srt[pos] = s;
    dstE[pos] = d;
  }
}

// ---------- conversions ----------
__global__ void convert_x_kernel(const float* __restrict__ x, unsigned short* __restrict__ xb) {
  int i = blockIdx.x * blockDim.x + threadIdx.x;
  float4 v = ((const float4*)x)[i];
  ushort4 o;
  o.x = f2bf(v.x); o.y = f2bf(v.y); o.z = f2bf(v.z); o.w = f2bf(v.w);
  ((ushort4*)xb)[i] = o;
}

__global__ void convert_w_kernel(const float* __restrict__ W1, const float* __restrict__ W2,
                                 const float* __restrict__ W3, unsigned short* __restrict__ Wt) {
  const float* W = (blockIdx.y == 0) ? W1 : (blockIdx.y == 1) ? W2 : W3;
  unsigned short* o = Wt + (size_t)blockIdx.y * DIM * DIM;
  int n = blockIdx.x;
  int k = threadIdx.x;
  o[n * DIM + k] = f2bf(W[k * DIM + n]);
}

// ---------- bf16 MFMA GEMM -> fp8 e4m3 output (h only ever consumed as fp8) ----------
__global__ __launch_bounds__(256)
void gemm_bf16_kernel(const unsigned short* __restrict__ A,
                      const unsigned short* __restrict__ Bt,
                      unsigned char* __restrict__ C8, int M) {
  __shared__ unsigned short As[128 * 32];
  __shared__ unsigned short Bs[128 * 32];
  int tid = threadIdx.x;
  int lane = tid & 63;
  int wave = tid >> 6;
  int bm = blockIdx.x * 128;
  int bn = blockIdx.y * 128;
  int wm = (wave & 1) * 64;
  int wn = (wave >> 1) * 64;
  int l16 = lane & 15;
  int lq  = lane >> 4;

  floatx4 acc[4][4];
#pragma unroll
  for (int mi = 0; mi < 4; ++mi)
#pragma unroll
    for (int ni = 0; ni < 4; ++ni)
      acc[mi][ni] = (floatx4){0.f, 0.f, 0.f, 0.f};

  for (int k0 = 0; k0 < DIM; k0 += 32) {
    __syncthreads();
#pragma unroll
    for (int i = 0; i < 2; ++i) {
      int c = i * 256 + tid;
      int r = c >> 2;
      int col = (c & 3) << 3;
      int ra = bm + r; if (ra >= M) ra = M - 1;
      __builtin_amdgcn_global_load_lds(
          (const __attribute__((address_space(1))) void*)(A + (size_t)ra * DIM + k0 + col),
          (__attribute__((address_space(3))) void*)(As + c * 8), 16, 0, 0);
      __builtin_amdgcn_global_load_lds(
          (const __attribute__((address_space(1))) void*)(Bt + (size_t)(bn + r) * DIM + k0 + col),
          (__attribute__((address_space(3))) void*)(Bs + c * 8), 16, 0, 0);
    }
    __syncthreads();
    short8 av[4], bv[4];
#pragma unroll
    for (int mi = 0; mi < 4; ++mi)
      av[mi] = *(const short8*)&As[(wm + mi * 16 + l16) * 32 + lq * 8];
#pragma unroll
    for (int ni = 0; ni < 4; ++ni)
      bv[ni] = *(const short8*)&Bs[(wn + ni * 16 + l16) * 32 + lq * 8];
#pragma unroll
    for (int mi = 0; mi < 4; ++mi)
#pragma unroll
      for (int ni = 0; ni < 4; ++ni)
        acc[mi][ni] = __builtin_amdgcn_mfma_f32_16x16x32_bf16(av[mi], bv[ni], acc[mi][ni], 0, 0, 0);
  }

  // C/D layout: col = lane&15, row = (lane>>4)*4 + reg; emit fp8 e4m3 bytes
#pragma unroll
  for (int mi = 0; mi < 4; ++mi) {
#pragma unroll
    for (int r = 0; r < 4; ++r) {
      int row = bm + wm + mi * 16 + lq * 4 + r;
      if (row < M) {
#pragma unroll
        for (int ni = 0; ni < 4; ++ni) {
          float fv = acc[mi][ni][r];
          int pk = __builtin_amdgcn_cvt_pk_fp8_f32(fv, fv, 0, false);
          C8[(size_t)row * DIM + bn + wn + ni * 16 + l16] = (unsigned char)(pk & 0xff);
        }
      }
    }
  }
}

// ---------- attention scores from fp8 h ----------
template <int H>
__global__ __launch_bounds__(256)
void score_kernel(const unsigned char* __restrict__ h8,
                  const float* __restrict__ asrc, const float* __restrict__ adst,
                  float* __restrict__ ssrc, float* __restrict__ sdst) {
  constexpr int LPH = 48 / H;
  int wave = threadIdx.x >> 6, lane = threadIdx.x & 63;
  int n = blockIdx.x * 4 + wave;
  bool colane = lane < 48;
  int lc = min(lane, 47);
  int j = lc * 8;

  __shared__ float r1[4][64], r2[4][64];
  float s1 = 0.f, s2 = 0.f;
  if (colane) {
    uint2 pk = *(const uint2*)(h8 + (size_t)n * DIM + j);
    floatx2 p0 = __builtin_amdgcn_cvt_pk_f32_fp8((int)pk.x, false);
    floatx2 p1 = __builtin_amdgcn_cvt_pk_f32_fp8((int)pk.x, true);
    floatx2 p2 = __builtin_amdgcn_cvt_pk_f32_fp8((int)pk.y, false);
    floatx2 p3 = __builtin_amdgcn_cvt_pk_f32_fp8((int)pk.y, true);
    float f[8] = {p0.x, p0.y, p1.x, p1.y, p2.x, p2.y, p3.x, p3.y};
    float4 a0 = *(const float4*)(asrc + j);
    float4 a1 = *(const float4*)(asrc + j + 4);
    float4 d0 = *(const float4*)(adst + j);
    float4 d1 = *(const float4*)(adst + j + 4);
    s1 = f[0]*a0.x + f[1]*a0.y + f[2]*a0.z + f[3]*a0.w
       + f[4]*a1.x + f[5]*a1.y + f[6]*a1.z + f[7]*a1.w;
    s2 = f[0]*d0.x + f[1]*d0.y + f[2]*d0.z + f[3]*d0.w
       + f[4]*d1.x + f[5]*d1.y + f[6]*d1.z + f[7]*d1.w;
  }
  r1[wave][lane] = colane ? s1 : 0.f;
  r2[wave][lane] = colane ? s2 : 0.f;
  asm volatile("s_waitcnt lgkmcnt(0)" ::: "memory");
  __builtin_amdgcn_wave_barrier();
  if (lane < H) {
    float a = 0.f;
#pragma unroll
    for (int k = 0; k < LPH; ++k) a += r1[wave][lane * LPH + k];
    ssrc[n * H + lane] = a;
  } else if (lane >= 8 && lane < 8 + H) {
    int h = lane - 8;
    float a = 0.f;
#pragma unroll
    for (int k = 0; k < LPH; ++k) a += r2[wave][h * LPH + k];
    sdst[n * H + h] = a;
  }
}

// ---------- edge-parallel unnormalized weights ----------
// One thread per CSR slot: w = exp(leaky(ssrc[src]+sdst[dst])). ssrc/sdst are
// L2-resident (<=1.2 MB); 550k independent threads — no serial chain.
template <int H>
__global__ __launch_bounds__(256)
void wexp_edge_kernel(const int* __restrict__ srt, const int* __restrict__ dstE,
                      const float* __restrict__ ssrc, const float* __restrict__ sdst,
                      float* __restrict__ walpha) {
  int i = blockIdx.x * 256 + threadIdx.x;
  if (i >= EPRIME) return;
  int s = srt[i];
  int d = dstE[i];
  auto wfun = [](float v) {
    v = fmaxf(v, SLOPE * v);
    return __expf(v);
  };
  if (H == 4) {
    float4 a = *(const float4*)(ssrc + (size_t)s * 4);
    float4 b = *(const float4*)(sdst + (size_t)d * 4);
    float4 o;
    o.x = wfun(a.x + b.x);
    o.y = wfun(a.y + b.y);
    o.z = wfun(a.z + b.z);
    o.w = wfun(a.w + b.w);
    *(float4*)(walpha + (size_t)i * 4) = o;
  } else {
    const floatx2* pa = (const floatx2*)(ssrc + (size_t)s * 6);
    const floatx2* pb = (const floatx2*)(sdst + (size_t)d * 6);
    floatx2* po = (floatx2*)(walpha + (size_t)i * 6);
#pragma unroll
    for (int k = 0; k < 3; ++k) {
      floatx2 a = pa[k], b = pb[k];
      floatx2 o;
      o.x = wfun(a.x + b.x);
      o.y = wfun(a.y + b.y);
      po[k] = o;
    }
  }
}

// ---------- pure weighted gather + fused epilogue (R0 core + index preload) ----------
// Neighbor list (contiguous in srt) preloaded ONCE into a per-lane register;
// per-batch indices come from v_readlane (ee wave-uniform -> SGPR lane index),
// so each 4-edge batch has ONE memory level (the row gathers) instead of two
// (index load -> gathers). Only +1 VGPR vs the R0 core; deg>64 falls back.
// den accumulated inline from the linear walpha stream (same edge order ->
// bit-identical numerics).
// MODE 0: outb = bf16(relu(LN(agg/den+bias)*g+be))
// MODE 1: outb = bf16(relu(agg/den+bias) + xresb)
template <int H, int MODE>
__global__ __launch_bounds__(256)
void aggregate_kernel(const int* __restrict__ row_ptr, const int* __restrict__ srt,
                      const float* __restrict__ walpha,
                      const unsigned char* __restrict__ h8, const float* __restrict__ bias,
                      const float* __restrict__ gamma, const float* __restrict__ beta,
                      const unsigned short* __restrict__ xresb,
                      unsigned short* __restrict__ outb) {
  constexpr int C = DIM / H;
  int wave = threadIdx.x >> 6;
  int lane = threadIdx.x & 63;
  int n = blockIdx.x * 4 + wave;
  int start = row_ptr[n];
  int deg = row_ptr[n + 1] - start;

  bool colane = lane < 48;
  int lc = min(lane, 47);
  int j = lc * 8;
  int myhead = j / C;

  float acc[8];
#pragma unroll
  for (int i = 0; i < 8; ++i) acc[i] = 0.f;
  float den = 0.f;

  const int* sp = srt + start;
  const float* ap = walpha + (size_t)start * H + myhead;

  // one coalesced load of the whole neighbor list (deg <= 64 fast path)
  int myidx = sp[min(lane, deg - 1)];
  int fast = min(deg, 64);

  auto accum = [&](uint2 pk, float w) {
    floatx2 p0 = __builtin_amdgcn_cvt_pk_f32_fp8((int)pk.x, false);
    floatx2 p1 = __builtin_amdgcn_cvt_pk_f32_fp8((int)pk.x, true);
    floatx2 p2 = __builtin_amdgcn_cvt_pk_f32_fp8((int)pk.y, false);
    floatx2 p3 = __builtin_amdgcn_cvt_pk_f32_fp8((int)pk.y, true);
    acc[0] = fmaf(w, p0.x, acc[0]); acc[1] = fmaf(w, p0.y, acc[1]);
    acc[2] = fmaf(w, p1.x, acc[2]); acc[3] = fmaf(w, p1.y, acc[3]);
    acc[4] = fmaf(w, p2.x, acc[4]); acc[5] = fmaf(w, p2.y, acc[5]);
    acc[6] = fmaf(w, p3.x, acc[6]); acc[7] = fmaf(w, p3.y, acc[7]);
  };

  int ee = 0;
  for (; ee + 4 <= fast; ee += 4) {
    int s0 = __builtin_amdgcn_readlane(myidx, ee);
    int s1 = __builtin_amdgcn_readlane(myidx, ee + 1);
    int s2 = __builtin_amdgcn_readlane(myidx, ee + 2);
    int s3 = __builtin_amdgcn_readlane(myidx, ee + 3);
    uint2 k0 = *(const uint2*)(h8 + (size_t)s0 * DIM + j);
    uint2 k1 = *(const uint2*)(h8 + (size_t)s1 * DIM + j);
    uint2 k2 = *(const uint2*)(h8 + (size_t)s2 * DIM + j);
    uint2 k3 = *(const uint2*)(h8 + (size_t)s3 * DIM + j);
    float w0 = ap[(ee) * H];
    float w1 = ap[(ee + 1) * H];
    float w2 = ap[(ee + 2) * H];
    float w3 = ap[(ee + 3) * H];
    den += w0; den += w1; den += w2; den += w3;
    accum(k0, w0); accum(k1, w1); accum(k2, w2); accum(k3, w3);
  }
  for (; ee < fast; ++ee) {
    int su = __builtin_amdgcn_readlane(myidx, ee);
    uint2 pk = *(const uint2*)(h8 + (size_t)su * DIM + j);
    float w = ap[ee * H];
    den += w;
    accum(pk, w);
  }
  // overflow path (deg > 64, essentially never for this graph): memory indices
  for (; ee < deg; ++ee) {
    int su = __builtin_amdgcn_readfirstlane(sp[ee]);
    uint2 pk = *(const uint2*)(h8 + (size_t)su * DIM + j);
    float w = ap[ee * H];
    den += w;
    accum(pk, w);
  }

  // epilogue: normalize by denom, then bias + LN/residual
  float invden = 1.f / (den + 1e-16f);
  float v[8];
  float4 b0 = *(const float4*)(bias + j);
  float4 b1 = *(const float4*)(bias + j + 4);
  v[0] = acc[0] * invden + b0.x; v[1] = acc[1] * invden + b0.y;
  v[2] = acc[2] * invden + b0.z; v[3] = acc[3] * invden + b0.w;
  v[4] = acc[4] * invden + b1.x; v[5] = acc[5] * invden + b1.y;
  v[6] = acc[6] * invden + b1.z; v[7] = acc[7] * invden + b1.w;

  if (MODE == 0) {
    float s1 = 0.f, s2 = 0.f;
    if (colane) {
#pragma unroll
      for (int i = 0; i < 8; ++i) { s1 += v[i]; s2 += v[i] * v[i]; }
    }
#pragma unroll
    for (int off = 32; off > 0; off >>= 1) {
      s1 += __shfl_xor(s1, off);
      s2 += __shfl_xor(s2, off);
    }
    float mu = s1 * (1.f / DIM);
    float var = s2 * (1.f / DIM) - mu * mu;
    float rs = rsqrtf(var + LN_EPS);
    if (colane) {
      float4 g0 = *(const float4*)(gamma + j);
      float4 g1 = *(const float4*)(gamma + j + 4);
      float4 e0 = *(const float4*)(beta + j);
      float4 e1 = *(const float4*)(beta + j + 4);
      float gg[8] = {g0.x, g0.y, g0.z, g0.w, g1.x, g1.y, g1.z, g1.w};
      float bb[8] = {e0.x, e0.y, e0.z, e0.w, e1.x, e1.y, e1.z, e1.w};
      ushort4 o0, o1;
      unsigned short oy[8];
#pragma unroll
      for (int i = 0; i < 8; ++i) {
        float y = (v[i] - mu) * rs * gg[i] + bb[i];
        oy[i] = f2bf(fmaxf(y, 0.f));
      }
      o0.x = oy[0]; o0.y = oy[1]; o0.z = oy[2]; o0.w = oy[3];
      o1.x = oy[4]; o1.y = oy[5]; o1.z = oy[6]; o1.w = oy[7];
      *(ushort4*)(outb + (size_t)n * DIM + j) = o0;
      *(ushort4*)(outb + (size_t)n * DIM + j + 4) = o1;
    }
  } else {
    if (colane) {
      uint4 xp = *(const uint4*)(xresb + (size_t)n * DIM + j);
      float xf[8];
      xf[0] = __uint_as_float(xp.x << 16); xf[1] = __uint_as_float(xp.x & 0xffff0000u);
      xf[2] = __uint_as_float(xp.y << 16); xf[3] = __uint_as_float(xp.y & 0xffff0000u);
      xf[4] = __uint_as_float(xp.z << 16); xf[5] = __uint_as_float(xp.z & 0xffff0000u);
      xf[6] = __uint_as_float(xp.w << 16); xf[7] = __uint_as_float(xp.w & 0xffff0000u);
      ushort4 o0, o1;
      unsigned short oy[8];
#pragma unroll
      for (int i = 0; i < 8; ++i) oy[i] = f2bf(fmaxf(v[i], 0.f) + xf[i]);
      o0.x = oy[0]; o0.y = oy[1]; o0.z = oy[2]; o0.w = oy[3];
      o1.x = oy[4]; o1.y = oy[5]; o1.z = oy[6]; o1.w = oy[7];
      *(ushort4*)(outb + (size_t)n * DIM + j) = o0;
      *(ushort4*)(outb + (size_t)n * DIM + j + 4) = o1;
    }
  }
}

// ---------- global mean pool (bf16 input) ----------
__global__ void pool_kernel(const unsigned short* __restrict__ xr, const void* __restrict__ batch,
                            const int* __restrict__ flag, float* __restrict__ out) {
  int b = blockIdx.x;
  int s = blockIdx.y;
  int t = threadIdx.x;
  int is64 = *flag;
  int lo, hi;
  { int l = 0, r = NNODES;
    while (l < r) { int m = (l + r) >> 1; if (load_i(batch, m, is64) < b) l = m + 1; else r = m; }
    lo = l; }
  { int l = lo, r = NNODES;
    while (l < r) { int m = (l + r) >> 1; if (load_i(batch, m, is64) < b + 1) l = m + 1; else r = m; }
    hi = l; }
  int cnt = hi - lo;
  float inv = 1.f / (float)max(cnt, 1);
  int chunk = (cnt + POOLS - 1) / POOLS;
  int r0 = lo + s * chunk;
  int r1 = min(r0 + chunk, hi);
  float acc = 0.f;
  for (int nn = r0; nn < r1; ++nn) acc += bf2f(xr[(size_t)nn * DIM + t]);
  if (r1 > r0) atomicAdd(&out[b * DIM + t], acc * inv);
}

// ---------- launch ----------
extern "C" void kernel_launch(void* const* d_in, const int* in_sizes, int n_in,
                              void* d_out, int out_size, void* d_ws, size_t ws_size,
                              hipStream_t stream) {
  const float* x    = (const float*)d_in[0];
  const void*  ei   = d_in[1];
  const void*  batch= d_in[2];
  const float* W1   = (const float*)d_in[3];
  const float* a1s  = (const float*)d_in[4];
  const float* a1d  = (const float*)d_in[5];
  const float* b1   = (const float*)d_in[6];
  const float* g1   = (const float*)d_in[7];
  const float* be1  = (const float*)d_in[8];
  const float* W2   = (const float*)d_in[9];
  const float* a2s  = (const float*)d_in[10];
  const float* a2d  = (const float*)d_in[11];
  const float* b2   = (const float*)d_in[12];
  const float* g2   = (const float*)d_in[13];
  const float* be2  = (const float*)d_in[14];
  const float* W3   = (const float*)d_in[15];
  const float* a3s  = (const float*)d_in[16];
  const float* a3d  = (const float*)d_in[17];
  const float* b3   = (const float*)d_in[18];
  float* out = (float*)d_out;

  char* ws = (char*)d_ws;
  size_t off = 0;
  auto alloc = [&](size_t bytes) -> void* {
    void* p = ws + off;
    off = (off + bytes + 255) & ~(size_t)255;
    return p;
  };
  int*   flag    = (int*)alloc(4);
  unsigned short* Xb = (unsigned short*)alloc((size_t)NNODES * DIM * 2);
  unsigned short* Qb = (unsigned short*)alloc((size_t)NNODES * DIM * 2);
  unsigned char*  P8 = (unsigned char*)alloc((size_t)NNODES * DIM);
  unsigned short* Wt = (unsigned short*)alloc((size_t)3 * DIM * DIM * 2);
  float* ssrc    = (float*)alloc((size_t)NNODES * 6 * 4);
  float* sdst    = (float*)alloc((size_t)NNODES * 6 * 4);
  float* walpha  = (float*)alloc((size_t)EPRIME * 6 * 4);
  int*   row_ptr = (int*)alloc((size_t)(NNODES + 1) * 4);
  int*   cursor  = (int*)alloc((size_t)NNODES * 4);
  int*   deg     = (int*)alloc((size_t)NNODES * 4);
  int*   btot    = (int*)alloc((size_t)NSCB * 4);
  int*   srt     = (int*)alloc((size_t)EPRIME * 4);
  int*   dstE    = (int*)alloc((size_t)EPRIME * 4);

  detect_kernel<<<1, 256, 0, stream>>>((const int*)ei, flag);
  hipMemsetAsync(deg, 0, (size_t)NNODES * 4, stream);
  hipMemsetAsync(d_out, 0, (size_t)out_size * 4, stream);
  int eblocks = (EPRIME + 255) / 256;
  count_kernel<<<eblocks, 256, 0, stream>>>(ei, flag, deg);
  scan1_kernel<<<NSCB, SCANB, 0, stream>>>(deg, row_ptr, btot);
  scan2_kernel<<<1, 256, 0, stream>>>(btot);
  scan3_kernel<<<NSCB, SCANB, 0, stream>>>(row_ptr, cursor, btot);
  scatter_kernel<<<eblocks, 256, 0, stream>>>(ei, flag, cursor, srt, dstE);

  convert_x_kernel<<<(NNODES * DIM / 4 + 255) / 256, 256, 0, stream>>>(x, Xb);
  convert_w_kernel<<<dim3(DIM, 3), DIM, 0, stream>>>(W1, W2, W3, Wt);

  dim3 ggrid((NNODES + 127) / 128, DIM / 128);
  int agrid = NNODES / 4;

  // layer 1
  gemm_bf16_kernel<<<ggrid, 256, 0, stream>>>(Xb, Wt, P8, NNODES);
  score_kernel<4><<<agrid, 256, 0, stream>>>(P8, a1s, a1d, ssrc, sdst);
  wexp_edge_kernel<4><<<eblocks, 256, 0, stream>>>(srt, dstE, ssrc, sdst, walpha);
  aggregate_kernel<4, 0><<<agrid, 256, 0, stream>>>(row_ptr, srt, walpha, P8, b1, g1, be1,
                                                    nullptr, Qb);
  // layer 2
  gemm_bf16_kernel<<<ggrid, 256, 0, stream>>>(Qb, Wt + (size_t)DIM * DIM, P8, NNODES);
  score_kernel<4><<<agrid, 256, 0, stream>>>(P8, a2s, a2d, ssrc, sdst);
  wexp_edge_kernel<4><<<eblocks, 256, 0, stream>>>(srt, dstE, ssrc, sdst, walpha);
  aggregate_kernel<4, 0><<<agrid, 256, 0, stream>>>(row_ptr, srt, walpha, P8, b2, g2, be2,
                                                    nullptr, Qb);
  // layer 3 (bf16 residual fused; output overwrites Qb)
  gemm_bf16_kernel<<<ggrid, 256, 0, stream>>>(Qb, Wt + (size_t)2 * DIM * DIM, P8, NNODES);
  score_kernel<6><<<agrid, 256, 0, stream>>>(P8, a3s, a3d, ssrc, sdst);
  wexp_edge_kernel<6><<<eblocks, 256, 0, stream>>>(srt, dstE, ssrc, sdst, walpha);
  aggregate_kernel<6, 1><<<agrid, 256, 0, stream>>>(row_ptr, srt, walpha, P8, b3, nullptr,
                                                    nullptr, Xb, Qb);
  // mean pool (bf16 input)
  pool_kernel<<<dim3(NB, POOLS), DIM, 0, stream>>>(Qb, batch, flag, out);
}

// Round 16
// 499.249 us; speedup vs baseline: 1.1041x; 1.0070x over previous
//
#include <hip/hip_runtime.h>

#define NNODES 50000
#define NEDGES 500000
#define DIM    384
#define NB     64
#define SLOPE  0.2f
#define LN_EPS 1e-5f
#define EPRIME (NEDGES + NNODES)
#define POOLS  16
#define SCANB  256
#define NSCB   ((NNODES + SCANB - 1) / SCANB)   // 196

typedef __attribute__((ext_vector_type(8))) short short8;
typedef __attribute__((ext_vector_type(4))) float floatx4;
typedef __attribute__((ext_vector_type(2))) float floatx2;

// ---------- helpers ----------
__device__ __forceinline__ int load_i(const void* p, long long i, int is64) {
  return is64 ? (int)((const long long*)p)[i] : ((const int*)p)[i];
}
__device__ __forceinline__ unsigned short f2bf(float f) {
  unsigned u = __float_as_uint(f);
  u += 0x7fffu + ((u >> 16) & 1u);
  return (unsigned short)(u >> 16);
}
__device__ __forceinline__ float bf2f(unsigned short u) {
  return __uint_as_float(((unsigned)u) << 16);
}

// ---------- fused prep: zero deg/out, convert W (3 layers), detect dtype ----------
__global__ void prep_kernel(const int* __restrict__ ei32, int* __restrict__ flag,
                            int* __restrict__ deg, float* __restrict__ out, int out_n,
                            const float* __restrict__ W1, const float* __restrict__ W2,
                            const float* __restrict__ W3, unsigned short* __restrict__ Wt) {
  int gid = blockIdx.x * 256 + threadIdx.x;
  int stride = gridDim.x * 256;
  for (int i = gid; i < NNODES; i += stride) deg[i] = 0;
  for (int i = gid; i < out_n; i += stride) out[i] = 0.f;
  // Wt[layer][n][k] = bf16(W[k*DIM + n])
  for (int i = gid; i < 3 * DIM * DIM; i += stride) {
    int layer = i / (DIM * DIM);
    int rem = i - layer * (DIM * DIM);
    int n = rem / DIM;
    int k = rem - n * DIM;
    const float* W = (layer == 0) ? W1 : (layer == 1) ? W2 : W3;
    Wt[i] = f2bf(W[k * DIM + n]);
  }
  if (blockIdx.x == 0) {
    __shared__ int nz;
    if (threadIdx.x == 0) nz = 0;
    __syncthreads();
    if (ei32[2 * threadIdx.x + 1] != 0) atomicAdd(&nz, 1);
    __syncthreads();
    if (threadIdx.x == 0) *flag = (nz == 0) ? 1 : 0;
  }
}

// ---------- CSR build ----------
__global__ void count_kernel(const void* __restrict__ ei, const int* __restrict__ flag,
                             int* __restrict__ deg) {
  int is64 = *flag;
  for (int i = blockIdx.x * blockDim.x + threadIdx.x; i < EPRIME; i += gridDim.x * blockDim.x) {
    int d = (i < NEDGES) ? load_i(ei, (long long)NEDGES + i, is64) : (i - NEDGES);
    atomicAdd(&deg[d], 1);
  }
}

__global__ void scan1_kernel(const int* __restrict__ deg, int* __restrict__ row_ptr,
                             int* __restrict__ btot) {
  __shared__ int buf[SCANB];
  int t = threadIdx.x, idx = blockIdx.x * SCANB + t;
  int v = (idx < NNODES) ? deg[idx] : 0;
  buf[t] = v;
  __syncthreads();
  for (int off = 1; off < SCANB; off <<= 1) {
    int x = (t >= off) ? buf[t - off] : 0;
    __syncthreads();
    buf[t] += x;
    __syncthreads();
  }
  if (idx < NNODES) row_ptr[idx] = buf[t] - v;
  if (t == SCANB - 1) btot[blockIdx.x] = buf[t];
}
__global__ void scan2_kernel(int* __restrict__ btot) {
  __shared__ int buf[256];
  int t = threadIdx.x;
  int v = (t < NSCB) ? btot[t] : 0;
  buf[t] = v;
  __syncthreads();
  for (int off = 1; off < 256; off <<= 1) {
    int x = (t >= off) ? buf[t - off] : 0;
    __syncthreads();
    buf[t] += x;
    __syncthreads();
  }
  if (t < NSCB) btot[t] = buf[t] - v;
}
__global__ void scan3_kernel(int* __restrict__ row_ptr, int* __restrict__ cursor,
                             const int* __restrict__ btot) {
  int idx = blockIdx.x * SCANB + threadIdx.x;
  if (idx < NNODES) {
    int v = row_ptr[idx] + btot[blockIdx.x];
    row_ptr[idx] = v;
    cursor[idx] = v;
  }
  if (idx == 0) row_ptr[NNODES] = EPRIME;
}

__global__ void scatter_kernel(const void* __restrict__ ei, const int* __restrict__ flag,
                               int* __restrict__ cursor, int* __restrict__ srt,
                               int* __restrict__ dstE) {
  int is64 = *flag;
  for (int i = blockIdx.x * blockDim.x + threadIdx.x; i < EPRIME; i += gridDim.x * blockDim.x) {
    int s, d;
    if (i < NEDGES) { s = load_i(ei, i, is64); d = load_i(ei, (long long)NEDGES + i, is64); }
    else            { s = d = i - NEDGES; }
    int pos = atomicAdd(&cursor[d], 1);
    srt[pos] = s;
    dstE[pos] = d;
  }
}

// ---------- conversions ----------
__global__ void convert_x_kernel(const float* __restrict__ x, unsigned short* __restrict__ xb) {
  int i = blockIdx.x * blockDim.x + threadIdx.x;
  float4 v = ((const float4*)x)[i];
  ushort4 o;
  o.x = f2bf(v.x); o.y = f2bf(v.y); o.z = f2bf(v.z); o.w = f2bf(v.w);
  ((ushort4*)xb)[i] = o;
}

// ---------- bf16 MFMA GEMM -> fp8 e4m3 output (h only ever consumed as fp8) ----------
__global__ __launch_bounds__(256)
void gemm_bf16_kernel(const unsigned short* __restrict__ A,
                      const unsigned short* __restrict__ Bt,
                      unsigned char* __restrict__ C8, int M) {
  __shared__ unsigned short As[128 * 32];
  __shared__ unsigned short Bs[128 * 32];
  int tid = threadIdx.x;
  int lane = tid & 63;
  int wave = tid >> 6;
  int bm = blockIdx.x * 128;
  int bn = blockIdx.y * 128;
  int wm = (wave & 1) * 64;
  int wn = (wave >> 1) * 64;
  int l16 = lane & 15;
  int lq  = lane >> 4;

  floatx4 acc[4][4];
#pragma unroll
  for (int mi = 0; mi < 4; ++mi)
#pragma unroll
    for (int ni = 0; ni < 4; ++ni)
      acc[mi][ni] = (floatx4){0.f, 0.f, 0.f, 0.f};

  for (int k0 = 0; k0 < DIM; k0 += 32) {
    __syncthreads();
#pragma unroll
    for (int i = 0; i < 2; ++i) {
      int c = i * 256 + tid;
      int r = c >> 2;
      int col = (c & 3) << 3;
      int ra = bm + r; if (ra >= M) ra = M - 1;
      __builtin_amdgcn_global_load_lds(
          (const __attribute__((address_space(1))) void*)(A + (size_t)ra * DIM + k0 + col),
          (__attribute__((address_space(3))) void*)(As + c * 8), 16, 0, 0);
      __builtin_amdgcn_global_load_lds(
          (const __attribute__((address_space(1))) void*)(Bt + (size_t)(bn + r) * DIM + k0 + col),
          (__attribute__((address_space(3))) void*)(Bs + c * 8), 16, 0, 0);
    }
    __syncthreads();
    short8 av[4], bv[4];
#pragma unroll
    for (int mi = 0; mi < 4; ++mi)
      av[mi] = *(const short8*)&As[(wm + mi * 16 + l16) * 32 + lq * 8];
#pragma unroll
    for (int ni = 0; ni < 4; ++ni)
      bv[ni] = *(const short8*)&Bs[(wn + ni * 16 + l16) * 32 + lq * 8];
#pragma unroll
    for (int mi = 0; mi < 4; ++mi)
#pragma unroll
      for (int ni = 0; ni < 4; ++ni)
        acc[mi][ni] = __builtin_amdgcn_mfma_f32_16x16x32_bf16(av[mi], bv[ni], acc[mi][ni], 0, 0, 0);
  }

  // C/D layout: col = lane&15, row = (lane>>4)*4 + reg; emit fp8 e4m3 bytes
#pragma unroll
  for (int mi = 0; mi < 4; ++mi) {
#pragma unroll
    for (int r = 0; r < 4; ++r) {
      int row = bm + wm + mi * 16 + lq * 4 + r;
      if (row < M) {
#pragma unroll
        for (int ni = 0; ni < 4; ++ni) {
          float fv = acc[mi][ni][r];
          int pk = __builtin_amdgcn_cvt_pk_fp8_f32(fv, fv, 0, false);
          C8[(size_t)row * DIM + bn + wn + ni * 16 + l16] = (unsigned char)(pk & 0xff);
        }
      }
    }
  }
}

// ---------- attention scores from fp8 h ----------
template <int H>
__global__ __launch_bounds__(256)
void score_kernel(const unsigned char* __restrict__ h8,
                  const float* __restrict__ asrc, const float* __restrict__ adst,
                  float* __restrict__ ssrc, float* __restrict__ sdst) {
  constexpr int LPH = 48 / H;
  int wave = threadIdx.x >> 6, lane = threadIdx.x & 63;
  int n = blockIdx.x * 4 + wave;
  bool colane = lane < 48;
  int lc = min(lane, 47);
  int j = lc * 8;

  __shared__ float r1[4][64], r2[4][64];
  float s1 = 0.f, s2 = 0.f;
  if (colane) {
    uint2 pk = *(const uint2*)(h8 + (size_t)n * DIM + j);
    floatx2 p0 = __builtin_amdgcn_cvt_pk_f32_fp8((int)pk.x, false);
    floatx2 p1 = __builtin_amdgcn_cvt_pk_f32_fp8((int)pk.x, true);
    floatx2 p2 = __builtin_amdgcn_cvt_pk_f32_fp8((int)pk.y, false);
    floatx2 p3 = __builtin_amdgcn_cvt_pk_f32_fp8((int)pk.y, true);
    float f[8] = {p0.x, p0.y, p1.x, p1.y, p2.x, p2.y, p3.x, p3.y};
    float4 a0 = *(const float4*)(asrc + j);
    float4 a1 = *(const float4*)(asrc + j + 4);
    float4 d0 = *(const float4*)(adst + j);
    float4 d1 = *(const float4*)(adst + j + 4);
    s1 = f[0]*a0.x + f[1]*a0.y + f[2]*a0.z + f[3]*a0.w
       + f[4]*a1.x + f[5]*a1.y + f[6]*a1.z + f[7]*a1.w;
    s2 = f[0]*d0.x + f[1]*d0.y + f[2]*d0.z + f[3]*d0.w
       + f[4]*d1.x + f[5]*d1.y + f[6]*d1.z + f[7]*d1.w;
  }
  r1[wave][lane] = colane ? s1 : 0.f;
  r2[wave][lane] = colane ? s2 : 0.f;
  asm volatile("s_waitcnt lgkmcnt(0)" ::: "memory");
  __builtin_amdgcn_wave_barrier();
  if (lane < H) {
    float a = 0.f;
#pragma unroll
    for (int k = 0; k < LPH; ++k) a += r1[wave][lane * LPH + k];
    ssrc[n * H + lane] = a;
  } else if (lane >= 8 && lane < 8 + H) {
    int h = lane - 8;
    float a = 0.f;
#pragma unroll
    for (int k = 0; k < LPH; ++k) a += r2[wave][h * LPH + k];
    sdst[n * H + h] = a;
  }
}

// ---------- edge-parallel unnormalized weights ----------
template <int H>
__global__ __launch_bounds__(256)
void wexp_edge_kernel(const int* __restrict__ srt, const int* __restrict__ dstE,
                      const float* __restrict__ ssrc, const float* __restrict__ sdst,
                      float* __restrict__ walpha) {
  int i = blockIdx.x * 256 + threadIdx.x;
  if (i >= EPRIME) return;
  int s = srt[i];
  int d = dstE[i];
  auto wfun = [](float v) {
    v = fmaxf(v, SLOPE * v);
    return __expf(v);
  };
  if (H == 4) {
    float4 a = *(const float4*)(ssrc + (size_t)s * 4);
    float4 b = *(const float4*)(sdst + (size_t)d * 4);
    float4 o;
    o.x = wfun(a.x + b.x);
    o.y = wfun(a.y + b.y);
    o.z = wfun(a.z + b.z);
    o.w = wfun(a.w + b.w);
    *(float4*)(walpha + (size_t)i * 4) = o;
  } else {
    const floatx2* pa = (const floatx2*)(ssrc + (size_t)s * 6);
    const floatx2* pb = (const floatx2*)(sdst + (size_t)d * 6);
    floatx2* po = (floatx2*)(walpha + (size_t)i * 6);
#pragma unroll
    for (int k = 0; k < 3; ++k) {
      floatx2 a = pa[k], b = pb[k];
      floatx2 o;
      o.x = wfun(a.x + b.x);
      o.y = wfun(a.y + b.y);
      po[k] = o;
    }
  }
}

// ---------- pure weighted gather + fused epilogue (R9 core + packed f32 FMA) ----------
// Accumulator held as 4x floatx2; acc2[i] += w2 * cvt_pk(...) selects
// v_pk_fma_f32 (VOP3P, 2 FMA/instr, full-rate on CDNA3+) — halves FMA issue
// count. Contraction == fmaf semantics, same order -> bit-identical.
// Index preload via v_readlane (R9, measured 47 µs); deg>64 falls back.
// MODE 0: outb = bf16(relu(LN(agg/den+bias)*g+be))
// MODE 1: outb = bf16(relu(agg/den+bias) + xresb)
template <int H, int MODE>
__global__ __launch_bounds__(256)
void aggregate_kernel(const int* __restrict__ row_ptr, const int* __restrict__ srt,
                      const float* __restrict__ walpha,
                      const unsigned char* __restrict__ h8, const float* __restrict__ bias,
                      const float* __restrict__ gamma, const float* __restrict__ beta,
                      const unsigned short* __restrict__ xresb,
                      unsigned short* __restrict__ outb) {
  constexpr int C = DIM / H;
  int wave = threadIdx.x >> 6;
  int lane = threadIdx.x & 63;
  int n = blockIdx.x * 4 + wave;
  int start = row_ptr[n];
  int deg = row_ptr[n + 1] - start;

  bool colane = lane < 48;
  int lc = min(lane, 47);
  int j = lc * 8;
  int myhead = j / C;

  floatx2 acc2[4];
#pragma unroll
  for (int i = 0; i < 4; ++i) acc2[i] = (floatx2){0.f, 0.f};
  float den = 0.f;

  const int* sp = srt + start;
  const float* ap = walpha + (size_t)start * H + myhead;

  // one coalesced load of the whole neighbor list (deg <= 64 fast path)
  int myidx = sp[min(lane, deg - 1)];
  int fast = min(deg, 64);

  auto accum = [&](uint2 pk, float w) {
    floatx2 w2;
    w2.x = w; w2.y = w;
    acc2[0] += w2 * __builtin_amdgcn_cvt_pk_f32_fp8((int)pk.x, false);
    acc2[1] += w2 * __builtin_amdgcn_cvt_pk_f32_fp8((int)pk.x, true);
    acc2[2] += w2 * __builtin_amdgcn_cvt_pk_f32_fp8((int)pk.y, false);
    acc2[3] += w2 * __builtin_amdgcn_cvt_pk_f32_fp8((int)pk.y, true);
  };

  int ee = 0;
  for (; ee + 4 <= fast; ee += 4) {
    int s0 = __builtin_amdgcn_readlane(myidx, ee);
    int s1 = __builtin_amdgcn_readlane(myidx, ee + 1);
    int s2 = __builtin_amdgcn_readlane(myidx, ee + 2);
    int s3 = __builtin_amdgcn_readlane(myidx, ee + 3);
    uint2 k0 = *(const uint2*)(h8 + (size_t)s0 * DIM + j);
    uint2 k1 = *(const uint2*)(h8 + (size_t)s1 * DIM + j);
    uint2 k2 = *(const uint2*)(h8 + (size_t)s2 * DIM + j);
    uint2 k3 = *(const uint2*)(h8 + (size_t)s3 * DIM + j);
    float w0 = ap[(ee) * H];
    float w1 = ap[(ee + 1) * H];
    float w2 = ap[(ee + 2) * H];
    float w3 = ap[(ee + 3) * H];
    den += w0; den += w1; den += w2; den += w3;
    accum(k0, w0); accum(k1, w1); accum(k2, w2); accum(k3, w3);
  }
  for (; ee < fast; ++ee) {
    int su = __builtin_amdgcn_readlane(myidx, ee);
    uint2 pk = *(const uint2*)(h8 + (size_t)su * DIM + j);
    float w = ap[ee * H];
    den += w;
    accum(pk, w);
  }
  // overflow path (deg > 64, essentially never for this graph): memory indices
  for (; ee < deg; ++ee) {
    int su = __builtin_amdgcn_readfirstlane(sp[ee]);
    uint2 pk = *(const uint2*)(h8 + (size_t)su * DIM + j);
    float w = ap[ee * H];
    den += w;
    accum(pk, w);
  }

  // epilogue: normalize by denom, then bias + LN/residual
  float invden = 1.f / (den + 1e-16f);
  float v[8];
  float4 b0 = *(const float4*)(bias + j);
  float4 b1 = *(const float4*)(bias + j + 4);
  v[0] = acc2[0].x * invden + b0.x; v[1] = acc2[0].y * invden + b0.y;
  v[2] = acc2[1].x * invden + b0.z; v[3] = acc2[1].y * invden + b0.w;
  v[4] = acc2[2].x * invden + b1.x; v[5] = acc2[2].y * invden + b1.y;
  v[6] = acc2[3].x * invden + b1.z; v[7] = acc2[3].y * invden + b1.w;

  if (MODE == 0) {
    float s1 = 0.f, s2 = 0.f;
    if (colane) {
#pragma unroll
      for (int i = 0; i < 8; ++i) { s1 += v[i]; s2 += v[i] * v[i]; }
    }
#pragma unroll
    for (int off = 32; off > 0; off >>= 1) {
      s1 += __shfl_xor(s1, off);
      s2 += __shfl_xor(s2, off);
    }
    float mu = s1 * (1.f / DIM);
    float var = s2 * (1.f / DIM) - mu * mu;
    float rs = rsqrtf(var + LN_EPS);
    if (colane) {
      float4 g0 = *(const float4*)(gamma + j);
      float4 g1 = *(const float4*)(gamma + j + 4);
      float4 e0 = *(const float4*)(beta + j);
      float4 e1 = *(const float4*)(beta + j + 4);
      float gg[8] = {g0.x, g0.y, g0.z, g0.w, g1.x, g1.y, g1.z, g1.w};
      float bb[8] = {e0.x, e0.y, e0.z, e0.w, e1.x, e1.y, e1.z, e1.w};
      ushort4 o0, o1;
      unsigned short oy[8];
#pragma unroll
      for (int i = 0; i < 8; ++i) {
        float y = (v[i] - mu) * rs * gg[i] + bb[i];
        oy[i] = f2bf(fmaxf(y, 0.f));
      }
      o0.x = oy[0]; o0.y = oy[1]; o0.z = oy[2]; o0.w = oy[3];
      o1.x = oy[4]; o1.y = oy[5]; o1.z = oy[6]; o1.w = oy[7];
      *(ushort4*)(outb + (size_t)n * DIM + j) = o0;
      *(ushort4*)(outb + (size_t)n * DIM + j + 4) = o1;
    }
  } else {
    if (colane) {
      uint4 xp = *(const uint4*)(xresb + (size_t)n * DIM + j);
      float xf[8];
      xf[0] = __uint_as_float(xp.x << 16); xf[1] = __uint_as_float(xp.x & 0xffff0000u);
      xf[2] = __uint_as_float(xp.y << 16); xf[3] = __uint_as_float(xp.y & 0xffff0000u);
      xf[4] = __uint_as_float(xp.z << 16); xf[5] = __uint_as_float(xp.z & 0xffff0000u);
      xf[6] = __uint_as_float(xp.w << 16); xf[7] = __uint_as_float(xp.w & 0xffff0000u);
      ushort4 o0, o1;
      unsigned short oy[8];
#pragma unroll
      for (int i = 0; i < 8; ++i) oy[i] = f2bf(fmaxf(v[i], 0.f) + xf[i]);
      o0.x = oy[0]; o0.y = oy[1]; o0.z = oy[2]; o0.w = oy[3];
      o1.x = oy[4]; o1.y = oy[5]; o1.z = oy[6]; o1.w = oy[7];
      *(ushort4*)(outb + (size_t)n * DIM + j) = o0;
      *(ushort4*)(outb + (size_t)n * DIM + j + 4) = o1;
    }
  }
}

// ---------- global mean pool (bf16 input) ----------
__global__ void pool_kernel(const unsigned short* __restrict__ xr, const void* __restrict__ batch,
                            const int* __restrict__ flag, float* __restrict__ out) {
  int b = blockIdx.x;
  int s = blockIdx.y;
  int t = threadIdx.x;
  int is64 = *flag;
  int lo, hi;
  { int l = 0, r = NNODES;
    while (l < r) { int m = (l + r) >> 1; if (load_i(batch, m, is64) < b) l = m + 1; else r = m; }
    lo = l; }
  { int l = lo, r = NNODES;
    while (l < r) { int m = (l + r) >> 1; if (load_i(batch, m, is64) < b + 1) l = m + 1; else r = m; }
    hi = l; }
  int cnt = hi - lo;
  float inv = 1.f / (float)max(cnt, 1);
  int chunk = (cnt + POOLS - 1) / POOLS;
  int r0 = lo + s * chunk;
  int r1 = min(r0 + chunk, hi);
  float acc = 0.f;
  for (int nn = r0; nn < r1; ++nn) acc += bf2f(xr[(size_t)nn * DIM + t]);
  if (r1 > r0) atomicAdd(&out[b * DIM + t], acc * inv);
}

// ---------- launch ----------
extern "C" void kernel_launch(void* const* d_in, const int* in_sizes, int n_in,
                              void* d_out, int out_size, void* d_ws, size_t ws_size,
                              hipStream_t stream) {
  const float* x    = (const float*)d_in[0];
  const void*  ei   = d_in[1];
  const void*  batch= d_in[2];
  const float* W1   = (const float*)d_in[3];
  const float* a1s  = (const float*)d_in[4];
  const float* a1d  = (const float*)d_in[5];
  const float* b1   = (const float*)d_in[6];
  const float* g1   = (const float*)d_in[7];
  const float* be1  = (const float*)d_in[8];
  const float* W2   = (const float*)d_in[9];
  const float* a2s  = (const float*)d_in[10];
  const float* a2d  = (const float*)d_in[11];
  const float* b2   = (const float*)d_in[12];
  const float* g2   = (const float*)d_in[13];
  const float* be2  = (const float*)d_in[14];
  const float* W3   = (const float*)d_in[15];
  const float* a3s  = (const float*)d_in[16];
  const float* a3d  = (const float*)d_in[17];
  const float* b3   = (const float*)d_in[18];
  float* out = (float*)d_out;

  char* ws = (char*)d_ws;
  size_t off = 0;
  auto alloc = [&](size_t bytes) -> void* {
    void* p = ws + off;
    off = (off + bytes + 255) & ~(size_t)255;
    return p;
  };
  int*   flag    = (int*)alloc(4);
  unsigned short* Xb = (unsigned short*)alloc((size_t)NNODES * DIM * 2);
  unsigned short* Qb = (unsigned short*)alloc((size_t)NNODES * DIM * 2);
  unsigned char*  P8 = (unsigned char*)alloc((size_t)NNODES * DIM);
  unsigned short* Wt = (unsigned short*)alloc((size_t)3 * DIM * DIM * 2);
  float* ssrc    = (float*)alloc((size_t)NNODES * 6 * 4);
  float* sdst    = (float*)alloc((size_t)NNODES * 6 * 4);
  float* walpha  = (float*)alloc((size_t)EPRIME * 6 * 4);
  int*   row_ptr = (int*)alloc((size_t)(NNODES + 1) * 4);
  int*   cursor  = (int*)alloc((size_t)NNODES * 4);
  int*   deg     = (int*)alloc((size_t)NNODES * 4);
  int*   btot    = (int*)alloc((size_t)NSCB * 4);
  int*   srt     = (int*)alloc((size_t)EPRIME * 4);
  int*   dstE    = (int*)alloc((size_t)EPRIME * 4);

  int eblocks = (EPRIME + 255) / 256;
  prep_kernel<<<1728, 256, 0, stream>>>((const int*)ei, flag, deg, out, out_size,
                                        W1, W2, W3, Wt);
  count_kernel<<<eblocks, 256, 0, stream>>>(ei, flag, deg);
  scan1_kernel<<<NSCB, SCANB, 0, stream>>>(deg, row_ptr, btot);
  scan2_kernel<<<1, 256, 0, stream>>>(btot);
  scan3_kernel<<<NSCB, SCANB, 0, stream>>>(row_ptr, cursor, btot);
  scatter_kernel<<<eblocks, 256, 0, stream>>>(ei, flag, cursor, srt, dstE);

  convert_x_kernel<<<(NNODES * DIM / 4 + 255) / 256, 256, 0, stream>>>(x, Xb);

  dim3 ggrid((NNODES + 127) / 128, DIM / 128);
  int agrid = NNODES / 4;

  // layer 1
  gemm_bf16_kernel<<<ggrid, 256, 0, stream>>>(Xb, Wt, P8, NNODES);
  score_kernel<4><<<agrid, 256, 0, stream>>>(P8, a1s, a1d, ssrc, sdst);
  wexp_edge_kernel<4><<<eblocks, 256, 0, stream>>>(srt, dstE, ssrc, sdst, walpha);
  aggregate_kernel<4, 0><<<agrid, 256, 0, stream>>>(row_ptr, srt, walpha, P8, b1, g1, be1,
                                                    nullptr, Qb);
  // layer 2
  gemm_bf16_kernel<<<ggrid, 256, 0, stream>>>(Qb, Wt + (size_t)DIM * DIM, P8, NNODES);
  score_kernel<4><<<agrid, 256, 0, stream>>>(P8, a2s, a2d, ssrc, sdst);
  wexp_edge_kernel<4><<<eblocks, 256, 0, stream>>>(srt, dstE, ssrc, sdst, walpha);
  aggregate_kernel<4, 0><<<agrid, 256, 0, stream>>>(row_ptr, srt, walpha, P8, b2, g2, be2,
                                                    nullptr, Qb);
  // layer 3 (bf16 residual fused; output overwrites Qb)
  gemm_bf16_kernel<<<ggrid, 256, 0, stream>>>(Qb, Wt + (size_t)2 * DIM * DIM, P8, NNODES);
  score_kernel<6><<<agrid, 256, 0, stream>>>(P8, a3s, a3d, ssrc, sdst);
  wexp_edge_kernel<6><<<eblocks, 256, 0, stream>>>(srt, dstE, ssrc, sdst, walpha);
  aggregate_kernel<6, 1><<<agrid, 256, 0, stream>>>(row_ptr, srt, walpha, P8, b3, nullptr,
                                                    nullptr, Xb, Qb);
  // mean pool (bf16 input)
  pool_kernel<<<dim3(NB, POOLS), DIM, 0, stream>>>(Qb, batch, flag, out);
}